// Round 1
// baseline (1166.974 us; speedup 1.0000x reference)
//
#include <hip/hip_runtime.h>
#include <math.h>

#define N_NODES 50000
#define N_EDGES 1600000
#define IN_DIM 256
#define HID_DIM 128
#define OUT_DIM 40

// ---------------- degree / normalization ----------------

__global__ void k_deg_init(float* __restrict__ deg) {
    int i = blockIdx.x * 256 + threadIdx.x;
    if (i < N_NODES) deg[i] = 1.0f;  // self-loop
}

__global__ void k_deg_count(const int* __restrict__ dst, float* __restrict__ deg) {
    int e = blockIdx.x * 256 + threadIdx.x;
    if (e < N_EDGES) atomicAdd(&deg[dst[e]], 1.0f);
}

__global__ void k_dinv(float* __restrict__ deg) {
    int i = blockIdx.x * 256 + threadIdx.x;
    if (i < N_NODES) deg[i] = rsqrtf(deg[i]);  // deg >= 1 always
}

// ---------------- GEMM1: h1[N][128] = x[N][256] @ W1[256][128] ----------------
// 128-row x 128-col tile per 256-thread block, 8x8 register blocking.

__global__ __launch_bounds__(256) void k_gemm1(const float* __restrict__ A,
                                               const float* __restrict__ B,
                                               float* __restrict__ C) {
    __shared__ float As[16][132];  // [k][row], +4 pad
    __shared__ float Bs[16][132];  // [k][col]
    const int tid  = threadIdx.x;
    const int row0 = blockIdx.x * 128;
    const int tx   = tid & 15;   // col group
    const int ty   = tid >> 4;   // row group

    float acc[8][8];
#pragma unroll
    for (int i = 0; i < 8; ++i)
#pragma unroll
        for (int j = 0; j < 8; ++j) acc[i][j] = 0.f;

    const int a_row = tid >> 1;        // 0..127
    const int a_kh  = (tid & 1) * 8;   // 0 or 8
    const int b_kk  = tid >> 4;        // 0..15
    const int b_col = (tid & 15) * 8;  // 0..120

    for (int k0 = 0; k0 < IN_DIM; k0 += 16) {
        // A tile -> As[k][row] (transposed store)
        {
            int grow = row0 + a_row;
            float v[8];
            if (grow < N_NODES) {
                const float4* p = (const float4*)(A + (long long)grow * IN_DIM + k0 + a_kh);
                float4 v0 = p[0], v1 = p[1];
                v[0] = v0.x; v[1] = v0.y; v[2] = v0.z; v[3] = v0.w;
                v[4] = v1.x; v[5] = v1.y; v[6] = v1.z; v[7] = v1.w;
            } else {
#pragma unroll
                for (int j = 0; j < 8; ++j) v[j] = 0.f;
            }
#pragma unroll
            for (int j = 0; j < 8; ++j) As[a_kh + j][a_row] = v[j];
        }
        // B tile -> Bs[k][col]
        {
            const float4* p = (const float4*)(B + (long long)(k0 + b_kk) * HID_DIM + b_col);
            float4 v0 = p[0], v1 = p[1];
            float* q = &Bs[b_kk][b_col];
            q[0] = v0.x; q[1] = v0.y; q[2] = v0.z; q[3] = v0.w;
            q[4] = v1.x; q[5] = v1.y; q[6] = v1.z; q[7] = v1.w;
        }
        __syncthreads();
#pragma unroll
        for (int kk = 0; kk < 16; ++kk) {
            float a[8], b[8];
#pragma unroll
            for (int j = 0; j < 8; ++j) a[j] = As[kk][ty * 8 + j];
#pragma unroll
            for (int j = 0; j < 8; ++j) b[j] = Bs[kk][tx * 8 + j];
#pragma unroll
            for (int i = 0; i < 8; ++i)
#pragma unroll
                for (int j = 0; j < 8; ++j) acc[i][j] = fmaf(a[i], b[j], acc[i][j]);
        }
        __syncthreads();
    }
#pragma unroll
    for (int i = 0; i < 8; ++i) {
        int grow = row0 + ty * 8 + i;
        if (grow < N_NODES) {
            float* c = C + (long long)grow * HID_DIM + tx * 8;
#pragma unroll
            for (int j = 0; j < 8; ++j) c[j] = acc[i][j];
        }
    }
}

// ---------------- aggregation layer 1 ----------------
// init: h1a = b1 + dinv^2 * h1  (self-loop message folded in)
__global__ void k_h1a_init(const float* __restrict__ h1, const float* __restrict__ dinv,
                           const float* __restrict__ b1, float* __restrict__ h1a) {
    long long t = (long long)blockIdx.x * 256 + threadIdx.x;  // t < N*128 (exact grid)
    int i = (int)(t >> 7), c = (int)(t & 127);
    float di = dinv[i];
    h1a[t] = b1[c] + di * di * h1[t];
}

// edges: 32 threads per edge, 4 cols each
__global__ void k_agg1(const int* __restrict__ src, const int* __restrict__ dst,
                       const float* __restrict__ dinv, const float* __restrict__ h1,
                       float* __restrict__ h1a) {
    long long t = (long long)blockIdx.x * 256 + threadIdx.x;
    int e = (int)(t >> 5);
    int c = (int)(t & 31);
    if (e >= N_EDGES) return;
    int s = src[e], d = dst[e];
    float coef = dinv[s] * dinv[d];
    const float* hs = h1 + (long long)s * HID_DIM;
    float* od = h1a + (long long)d * HID_DIM;
#pragma unroll
    for (int j = 0; j < 4; ++j) {
        int col = c + j * 32;
        atomicAdd(&od[col], coef * hs[col]);
    }
}

// ---------------- GEMM2: h2[N][40] = relu(h1a)[N][128] @ W2[128][40] ----------------
__global__ __launch_bounds__(320) void k_gemm2(const float* __restrict__ h1a,
                                               const float* __restrict__ W2,
                                               float* __restrict__ h2) {
    int t = threadIdx.x;
    int r = t / OUT_DIM;           // 0..7
    int c = t - r * OUT_DIM;       // 0..39
    int row = blockIdx.x * 8 + r;
    if (row >= N_NODES) return;
    const float* h = h1a + (long long)row * HID_DIM;
    float acc = 0.f;
#pragma unroll 8
    for (int k = 0; k < HID_DIM; ++k)
        acc = fmaf(fmaxf(h[k], 0.f), W2[k * OUT_DIM + c], acc);
    h2[(long long)row * OUT_DIM + c] = acc;
}

// ---------------- aggregation layer 2 (into d_out) ----------------
__global__ void k_out_init(const float* __restrict__ h2, const float* __restrict__ dinv,
                           const float* __restrict__ b2, float* __restrict__ out) {
    long long t = (long long)blockIdx.x * 256 + threadIdx.x;
    if (t >= (long long)N_NODES * OUT_DIM) return;
    int i = (int)(t / OUT_DIM), c = (int)(t % OUT_DIM);
    float di = dinv[i];
    out[t] = b2[c] + di * di * h2[t];
}

__global__ void k_agg2(const int* __restrict__ src, const int* __restrict__ dst,
                       const float* __restrict__ dinv, const float* __restrict__ h2,
                       float* __restrict__ out) {
    long long t = (long long)blockIdx.x * 256 + threadIdx.x;
    int e = (int)(t >> 5);
    int c = (int)(t & 31);
    if (e >= N_EDGES) return;
    int s = src[e], d = dst[e];
    float coef = dinv[s] * dinv[d];
    const float* hs = h2 + (long long)s * OUT_DIM;
    float* od = out + (long long)d * OUT_DIM;
    if (c < OUT_DIM) atomicAdd(&od[c], coef * hs[c]);
    if (c < OUT_DIM - 32) atomicAdd(&od[c + 32], coef * hs[c + 32]);
}

// ---------------- row-wise log_softmax over 40 cols, one wave per row ----------------
__global__ __launch_bounds__(256) void k_logsoftmax(float* __restrict__ out) {
    int row  = blockIdx.x * 4 + (threadIdx.x >> 6);
    int lane = threadIdx.x & 63;
    if (row >= N_NODES) return;
    float* o = out + (long long)row * OUT_DIM;
    float v = (lane < OUT_DIM) ? o[lane] : -INFINITY;
    float m = v;
#pragma unroll
    for (int off = 32; off > 0; off >>= 1) m = fmaxf(m, __shfl_xor(m, off));
    float ex = (lane < OUT_DIM) ? expf(v - m) : 0.0f;
    float s = ex;
#pragma unroll
    for (int off = 32; off > 0; off >>= 1) s += __shfl_xor(s, off);
    float ls = logf(s);
    if (lane < OUT_DIM) o[lane] = v - m - ls;
}

// ---------------- launch ----------------

extern "C" void kernel_launch(void* const* d_in, const int* in_sizes, int n_in,
                              void* d_out, int out_size, void* d_ws, size_t ws_size,
                              hipStream_t stream) {
    const float* x  = (const float*)d_in[0];
    const int*   ei = (const int*)d_in[1];
    const float* W1 = (const float*)d_in[2];
    const float* b1 = (const float*)d_in[3];
    const float* W2 = (const float*)d_in[4];
    const float* b2 = (const float*)d_in[5];
    float* out = (float*)d_out;

    const int* esrc = ei;             // edge_index[0]
    const int* edst = ei + N_EDGES;   // edge_index[1]

    float* dinv = (float*)d_ws;                              // N
    float* h1   = dinv + N_NODES;                            // N*128
    float* h1a  = h1 + (size_t)N_NODES * HID_DIM;            // N*128
    float* h2   = h1a + (size_t)N_NODES * HID_DIM;           // N*40

    k_deg_init<<<(N_NODES + 255) / 256, 256, 0, stream>>>(dinv);
    k_deg_count<<<(N_EDGES + 255) / 256, 256, 0, stream>>>(edst, dinv);
    k_dinv<<<(N_NODES + 255) / 256, 256, 0, stream>>>(dinv);

    k_gemm1<<<(N_NODES + 127) / 128, 256, 0, stream>>>(x, W1, h1);

    k_h1a_init<<<(N_NODES * HID_DIM) / 256, 256, 0, stream>>>(h1, dinv, b1, h1a);
    k_agg1<<<(int)((long long)N_EDGES * 32 / 256), 256, 0, stream>>>(esrc, edst, dinv, h1, h1a);

    k_gemm2<<<(N_NODES + 7) / 8, 320, 0, stream>>>(h1a, W2, h2);

    k_out_init<<<(int)(((long long)N_NODES * OUT_DIM + 255) / 256), 256, 0, stream>>>(h2, dinv, b2, out);
    k_agg2<<<(int)((long long)N_EDGES * 32 / 256), 256, 0, stream>>>(esrc, edst, dinv, h2, out);

    k_logsoftmax<<<(N_NODES + 3) / 4, 256, 0, stream>>>(out);
}

// Round 2
// 522.718 us; speedup vs baseline: 2.2325x; 2.2325x over previous
//
#include <hip/hip_runtime.h>
#include <math.h>

#define N_NODES 50000
#define N_EDGES 1600000
#define IN_DIM 256
#define HID_DIM 128
#define OUT_DIM 40
#define SCAN_BLK 1024
#define N_SCAN_BLKS ((N_NODES + SCAN_BLK - 1) / SCAN_BLK)  // 49

// ---------------- CSR build: count, scan, fill ----------------

__global__ void k_zero(int* __restrict__ p, int n) {
    int i = blockIdx.x * 256 + threadIdx.x;
    if (i < n) p[i] = 0;
}

__global__ void k_count(const int* __restrict__ dst, int* __restrict__ count) {
    int e = blockIdx.x * 256 + threadIdx.x;
    if (e < N_EDGES) atomicAdd(&count[dst[e]], 1);
}

// per-block exclusive scan over 1024-element chunks (256 thr x 4 elems)
__global__ __launch_bounds__(256) void k_scan1(const int* __restrict__ count,
                                               int* __restrict__ excl,
                                               int* __restrict__ partial) {
    __shared__ int sh[256];
    const int tid = threadIdx.x;
    const int base = blockIdx.x * SCAN_BLK + tid * 4;
    int v[4], sum = 0;
#pragma unroll
    for (int j = 0; j < 4; ++j) {
        v[j] = (base + j < N_NODES) ? count[base + j] : 0;
        sum += v[j];
    }
    sh[tid] = sum;
    __syncthreads();
    for (int off = 1; off < 256; off <<= 1) {
        int t = (tid >= off) ? sh[tid - off] : 0;
        __syncthreads();
        sh[tid] += t;
        __syncthreads();
    }
    int run = sh[tid] - sum;  // exclusive prefix of this thread's chunk
#pragma unroll
    for (int j = 0; j < 4; ++j) {
        if (base + j < N_NODES) excl[base + j] = run;
        run += v[j];
    }
    if (tid == 255) partial[blockIdx.x] = sh[255];
}

// serial scan of the 49 block partials (tiny)
__global__ void k_scan2(int* __restrict__ partial) {
    if (threadIdx.x == 0) {
        int run = 0;
        for (int i = 0; i < N_SCAN_BLKS; ++i) {
            int v = partial[i];
            partial[i] = run;
            run += v;
        }
    }
}

// finalize row_ptr/cursor/dinv
__global__ void k_scan3(const int* __restrict__ count, const int* __restrict__ excl,
                        const int* __restrict__ partial, int* __restrict__ row_ptr,
                        int* __restrict__ cursor, float* __restrict__ dinv) {
    int i = blockIdx.x * 256 + threadIdx.x;
    if (i < N_NODES) {
        int rp = excl[i] + partial[i >> 10];
        row_ptr[i] = rp;
        cursor[i] = rp;
        dinv[i] = rsqrtf((float)count[i] + 1.0f);  // +1 self-loop
    }
    if (i == 0) row_ptr[N_NODES] = N_EDGES;
}

// scatter (src, coef) into CSR slots
__global__ void k_fill(const int* __restrict__ src, const int* __restrict__ dst,
                       const float* __restrict__ dinv, int* __restrict__ cursor,
                       float2* __restrict__ csr) {
    int e = blockIdx.x * 256 + threadIdx.x;
    if (e >= N_EDGES) return;
    int s = src[e], d = dst[e];
    int pos = atomicAdd(&cursor[d], 1);
    csr[pos] = make_float2(__int_as_float(s), dinv[s] * dinv[d]);
}

// ---------------- GEMM1: h1[N][128] = x[N][256] @ W1[256][128] ----------------

__global__ __launch_bounds__(256) void k_gemm1(const float* __restrict__ A,
                                               const float* __restrict__ B,
                                               float* __restrict__ C) {
    __shared__ float As[16][132];
    __shared__ float Bs[16][132];
    const int tid  = threadIdx.x;
    const int row0 = blockIdx.x * 128;
    const int tx   = tid & 15;
    const int ty   = tid >> 4;

    float acc[8][8];
#pragma unroll
    for (int i = 0; i < 8; ++i)
#pragma unroll
        for (int j = 0; j < 8; ++j) acc[i][j] = 0.f;

    const int a_row = tid >> 1;
    const int a_kh  = (tid & 1) * 8;
    const int b_kk  = tid >> 4;
    const int b_col = (tid & 15) * 8;

    for (int k0 = 0; k0 < IN_DIM; k0 += 16) {
        {
            int grow = row0 + a_row;
            float v[8];
            if (grow < N_NODES) {
                const float4* p = (const float4*)(A + (long long)grow * IN_DIM + k0 + a_kh);
                float4 v0 = p[0], v1 = p[1];
                v[0] = v0.x; v[1] = v0.y; v[2] = v0.z; v[3] = v0.w;
                v[4] = v1.x; v[5] = v1.y; v[6] = v1.z; v[7] = v1.w;
            } else {
#pragma unroll
                for (int j = 0; j < 8; ++j) v[j] = 0.f;
            }
#pragma unroll
            for (int j = 0; j < 8; ++j) As[a_kh + j][a_row] = v[j];
        }
        {
            const float4* p = (const float4*)(B + (long long)(k0 + b_kk) * HID_DIM + b_col);
            float4 v0 = p[0], v1 = p[1];
            float* q = &Bs[b_kk][b_col];
            q[0] = v0.x; q[1] = v0.y; q[2] = v0.z; q[3] = v0.w;
            q[4] = v1.x; q[5] = v1.y; q[6] = v1.z; q[7] = v1.w;
        }
        __syncthreads();
#pragma unroll
        for (int kk = 0; kk < 16; ++kk) {
            float a[8], b[8];
#pragma unroll
            for (int j = 0; j < 8; ++j) a[j] = As[kk][ty * 8 + j];
#pragma unroll
            for (int j = 0; j < 8; ++j) b[j] = Bs[kk][tx * 8 + j];
#pragma unroll
            for (int i = 0; i < 8; ++i)
#pragma unroll
                for (int j = 0; j < 8; ++j) acc[i][j] = fmaf(a[i], b[j], acc[i][j]);
        }
        __syncthreads();
    }
#pragma unroll
    for (int i = 0; i < 8; ++i) {
        int grow = row0 + ty * 8 + i;
        if (grow < N_NODES) {
            float* c = C + (long long)grow * HID_DIM + tx * 8;
#pragma unroll
            for (int j = 0; j < 8; ++j) c[j] = acc[i][j];
        }
    }
}

// ---------------- gather-aggregate layer 1 (+bias, +self-loop, +ReLU) ----------------
// one wave per destination node; lane handles cols {lane, lane+64}

__global__ __launch_bounds__(256) void k_gather1(const float* __restrict__ h1,
                                                 const float* __restrict__ dinv,
                                                 const float* __restrict__ b1,
                                                 const int* __restrict__ row_ptr,
                                                 const float2* __restrict__ csr,
                                                 float* __restrict__ h1a) {
    const int node = blockIdx.x * 4 + (threadIdx.x >> 6);  // grid exact: 12500*4 = 50000
    const int lane = threadIdx.x & 63;
    const float di = dinv[node];
    const float* hn = h1 + (long long)node * HID_DIM;
    float a0 = fmaf(di * di, hn[lane], b1[lane]);
    float a1 = fmaf(di * di, hn[lane + 64], b1[lane + 64]);

    int j  = row_ptr[node];
    const int je = row_ptr[node + 1];
    for (; j + 1 < je; j += 2) {
        float2 c0 = csr[j], c1 = csr[j + 1];
        const float* p0 = h1 + (long long)__float_as_int(c0.x) * HID_DIM;
        const float* p1 = h1 + (long long)__float_as_int(c1.x) * HID_DIM;
        float u0 = p0[lane], u1 = p0[lane + 64];
        float w0 = p1[lane], w1 = p1[lane + 64];
        a0 = fmaf(c0.y, u0, a0);
        a1 = fmaf(c0.y, u1, a1);
        a0 = fmaf(c1.y, w0, a0);
        a1 = fmaf(c1.y, w1, a1);
    }
    if (j < je) {
        float2 c0 = csr[j];
        const float* p0 = h1 + (long long)__float_as_int(c0.x) * HID_DIM;
        a0 = fmaf(c0.y, p0[lane], a0);
        a1 = fmaf(c0.y, p0[lane + 64], a1);
    }
    float* o = h1a + (long long)node * HID_DIM;
    o[lane]      = fmaxf(a0, 0.f);
    o[lane + 64] = fmaxf(a1, 0.f);
}

// ---------------- GEMM2: h2[N][40] = h1a[N][128] @ W2[128][40] (h1a pre-ReLU'd) ----------------

__global__ __launch_bounds__(320) void k_gemm2(const float* __restrict__ h1a,
                                               const float* __restrict__ W2,
                                               float* __restrict__ h2) {
    int t = threadIdx.x;
    int r = t / OUT_DIM;
    int c = t - r * OUT_DIM;
    int row = blockIdx.x * 8 + r;
    if (row >= N_NODES) return;
    const float* h = h1a + (long long)row * HID_DIM;
    float acc = 0.f;
#pragma unroll 8
    for (int k = 0; k < HID_DIM; ++k)
        acc = fmaf(h[k], W2[k * OUT_DIM + c], acc);
    h2[(long long)row * OUT_DIM + c] = acc;
}

// ---------------- gather-aggregate layer 2 (+bias, +self-loop) + log_softmax ----------------

__global__ __launch_bounds__(256) void k_gather2(const float* __restrict__ h2,
                                                 const float* __restrict__ dinv,
                                                 const float* __restrict__ b2,
                                                 const int* __restrict__ row_ptr,
                                                 const float2* __restrict__ csr,
                                                 float* __restrict__ out) {
    const int node = blockIdx.x * 4 + (threadIdx.x >> 6);
    const int lane = threadIdx.x & 63;
    const bool act = lane < OUT_DIM;
    const float di = dinv[node];
    float a = act ? fmaf(di * di, h2[(long long)node * OUT_DIM + lane], b2[lane]) : 0.f;

    int j  = row_ptr[node];
    const int je = row_ptr[node + 1];
    for (; j + 1 < je; j += 2) {
        float2 c0 = csr[j], c1 = csr[j + 1];
        const float* p0 = h2 + (long long)__float_as_int(c0.x) * OUT_DIM;
        const float* p1 = h2 + (long long)__float_as_int(c1.x) * OUT_DIM;
        if (act) {
            a = fmaf(c0.y, p0[lane], a);
            a = fmaf(c1.y, p1[lane], a);
        }
    }
    if (j < je) {
        float2 c0 = csr[j];
        if (act) a = fmaf(c0.y, h2[(long long)__float_as_int(c0.x) * OUT_DIM + lane], a);
    }

    // fused row log_softmax over lanes 0..39
    float v = act ? a : -INFINITY;
    float m = v;
#pragma unroll
    for (int off = 32; off > 0; off >>= 1) m = fmaxf(m, __shfl_xor(m, off));
    float ex = act ? expf(v - m) : 0.f;
    float s = ex;
#pragma unroll
    for (int off = 32; off > 0; off >>= 1) s += __shfl_xor(s, off);
    float ls = logf(s);
    if (act) out[(long long)node * OUT_DIM + lane] = v - m - ls;
}

// ---------------- launch ----------------

extern "C" void kernel_launch(void* const* d_in, const int* in_sizes, int n_in,
                              void* d_out, int out_size, void* d_ws, size_t ws_size,
                              hipStream_t stream) {
    const float* x  = (const float*)d_in[0];
    const int*   ei = (const int*)d_in[1];
    const float* W1 = (const float*)d_in[2];
    const float* b1 = (const float*)d_in[3];
    const float* W2 = (const float*)d_in[4];
    const float* b2 = (const float*)d_in[5];
    float* out = (float*)d_out;

    const int* esrc = ei;
    const int* edst = ei + N_EDGES;

    // workspace layout
    char* w = (char*)d_ws;
    int*    count   = (int*)w;                     w += sizeof(int) * N_NODES;
    int*    excl    = (int*)w;                     w += sizeof(int) * N_NODES;
    int*    partial = (int*)w;                     w += sizeof(int) * 64;
    int*    row_ptr = (int*)w;                     w += sizeof(int) * (N_NODES + 1);
    int*    cursor  = (int*)w;                     w += sizeof(int) * N_NODES;
    float*  dinv    = (float*)w;                   w += sizeof(float) * N_NODES;
    float2* csr     = (float2*)w;                  w += sizeof(float2) * N_EDGES;
    float*  h1      = (float*)w;                   w += sizeof(float) * (size_t)N_NODES * HID_DIM;
    float*  h1a     = (float*)w;                   w += sizeof(float) * (size_t)N_NODES * HID_DIM;
    float*  h2      = (float*)w;                   w += sizeof(float) * (size_t)N_NODES * OUT_DIM;

    const int nblk_nodes = (N_NODES + 255) / 256;
    const int nblk_edges = (N_EDGES + 255) / 256;

    // CSR build
    k_zero<<<nblk_nodes, 256, 0, stream>>>(count, N_NODES);
    k_count<<<nblk_edges, 256, 0, stream>>>(edst, count);
    k_scan1<<<N_SCAN_BLKS, 256, 0, stream>>>(count, excl, partial);
    k_scan2<<<1, 64, 0, stream>>>(partial);
    k_scan3<<<nblk_nodes, 256, 0, stream>>>(count, excl, partial, row_ptr, cursor, dinv);
    k_fill<<<nblk_edges, 256, 0, stream>>>(esrc, edst, dinv, cursor, csr);

    // layer 1
    k_gemm1<<<(N_NODES + 127) / 128, 256, 0, stream>>>(x, W1, h1);
    k_gather1<<<N_NODES / 4, 256, 0, stream>>>(h1, dinv, b1, row_ptr, csr, h1a);

    // layer 2 + fused log_softmax
    k_gemm2<<<(N_NODES + 7) / 8, 320, 0, stream>>>(h1a, W2, h2);
    k_gather2<<<N_NODES / 4, 256, 0, stream>>>(h2, dinv, b2, row_ptr, csr, out);
}

// Round 3
// 450.283 us; speedup vs baseline: 2.5916x; 1.1609x over previous
//
#include <hip/hip_runtime.h>
#include <math.h>

#define N_NODES 50000
#define N_EDGES 1600000
#define IN_DIM 256
#define HID_DIM 128
#define OUT_DIM 40
#define H2_STRIDE 64  // bf16 h2 rows padded to 128B (one cache line)
#define SCAN_BLK 1024
#define N_SCAN_BLKS ((N_NODES + SCAN_BLK - 1) / SCAN_BLK)  // 49

// ---------------- bf16 helpers (RNE) ----------------
__device__ __forceinline__ unsigned short f2bf(float f) {
    unsigned int u = __float_as_uint(f);
    unsigned int r = u + 0x7FFFu + ((u >> 16) & 1u);
    return (unsigned short)(r >> 16);
}
__device__ __forceinline__ float bf2f(unsigned short s) {
    return __uint_as_float(((unsigned int)s) << 16);
}

// ---------------- CSR build: count, scan, fill ----------------

__global__ void k_zero(int* __restrict__ p, int n) {
    int i = blockIdx.x * 256 + threadIdx.x;
    if (i < n) p[i] = 0;
}

__global__ void k_count(const int* __restrict__ dst, int* __restrict__ count) {
    int e = blockIdx.x * 256 + threadIdx.x;
    if (e < N_EDGES) atomicAdd(&count[dst[e]], 1);
}

__global__ __launch_bounds__(256) void k_scan1(const int* __restrict__ count,
                                               int* __restrict__ excl,
                                               int* __restrict__ partial) {
    __shared__ int sh[256];
    const int tid = threadIdx.x;
    const int base = blockIdx.x * SCAN_BLK + tid * 4;
    int v[4], sum = 0;
#pragma unroll
    for (int j = 0; j < 4; ++j) {
        v[j] = (base + j < N_NODES) ? count[base + j] : 0;
        sum += v[j];
    }
    sh[tid] = sum;
    __syncthreads();
    for (int off = 1; off < 256; off <<= 1) {
        int t = (tid >= off) ? sh[tid - off] : 0;
        __syncthreads();
        sh[tid] += t;
        __syncthreads();
    }
    int run = sh[tid] - sum;
#pragma unroll
    for (int j = 0; j < 4; ++j) {
        if (base + j < N_NODES) excl[base + j] = run;
        run += v[j];
    }
    if (tid == 255) partial[blockIdx.x] = sh[255];
}

__global__ void k_scan2(int* __restrict__ partial) {
    if (threadIdx.x == 0) {
        int run = 0;
        for (int i = 0; i < N_SCAN_BLKS; ++i) {
            int v = partial[i];
            partial[i] = run;
            run += v;
        }
    }
}

__global__ void k_scan3(const int* __restrict__ count, const int* __restrict__ excl,
                        const int* __restrict__ partial, int* __restrict__ row_ptr,
                        int* __restrict__ cursor, float* __restrict__ dinv) {
    int i = blockIdx.x * 256 + threadIdx.x;
    if (i < N_NODES) {
        int rp = excl[i] + partial[i >> 10];
        row_ptr[i] = rp;
        cursor[i] = rp;
        dinv[i] = rsqrtf((float)count[i] + 1.0f);
    }
    if (i == 0) row_ptr[N_NODES] = N_EDGES;
}

__global__ void k_fill(const int* __restrict__ src, const int* __restrict__ dst,
                       const float* __restrict__ dinv, int* __restrict__ cursor,
                       float2* __restrict__ csr) {
    int e = blockIdx.x * 256 + threadIdx.x;
    if (e >= N_EDGES) return;
    int s = src[e], d = dst[e];
    int pos = atomicAdd(&cursor[d], 1);
    csr[pos] = make_float2(__int_as_float(s), dinv[s] * dinv[d]);
}

// ---------------- GEMM1: h1b[N][128](bf16) = x[N][256] @ W1[256][128] ----------------

__global__ __launch_bounds__(256) void k_gemm1(const float* __restrict__ A,
                                               const float* __restrict__ B,
                                               unsigned short* __restrict__ Cb) {
    __shared__ float As[16][132];
    __shared__ float Bs[16][132];
    const int tid  = threadIdx.x;
    const int row0 = blockIdx.x * 128;
    const int tx   = tid & 15;
    const int ty   = tid >> 4;

    float acc[8][8];
#pragma unroll
    for (int i = 0; i < 8; ++i)
#pragma unroll
        for (int j = 0; j < 8; ++j) acc[i][j] = 0.f;

    const int a_row = tid >> 1;
    const int a_kh  = (tid & 1) * 8;
    const int b_kk  = tid >> 4;
    const int b_col = (tid & 15) * 8;

    for (int k0 = 0; k0 < IN_DIM; k0 += 16) {
        {
            int grow = row0 + a_row;
            float v[8];
            if (grow < N_NODES) {
                const float4* p = (const float4*)(A + (long long)grow * IN_DIM + k0 + a_kh);
                float4 v0 = p[0], v1 = p[1];
                v[0] = v0.x; v[1] = v0.y; v[2] = v0.z; v[3] = v0.w;
                v[4] = v1.x; v[5] = v1.y; v[6] = v1.z; v[7] = v1.w;
            } else {
#pragma unroll
                for (int j = 0; j < 8; ++j) v[j] = 0.f;
            }
#pragma unroll
            for (int j = 0; j < 8; ++j) As[a_kh + j][a_row] = v[j];
        }
        {
            const float4* p = (const float4*)(B + (long long)(k0 + b_kk) * HID_DIM + b_col);
            float4 v0 = p[0], v1 = p[1];
            float* q = &Bs[b_kk][b_col];
            q[0] = v0.x; q[1] = v0.y; q[2] = v0.z; q[3] = v0.w;
            q[4] = v1.x; q[5] = v1.y; q[6] = v1.z; q[7] = v1.w;
        }
        __syncthreads();
#pragma unroll
        for (int kk = 0; kk < 16; ++kk) {
            float a[8], b[8];
#pragma unroll
            for (int j = 0; j < 8; ++j) a[j] = As[kk][ty * 8 + j];
#pragma unroll
            for (int j = 0; j < 8; ++j) b[j] = Bs[kk][tx * 8 + j];
#pragma unroll
            for (int i = 0; i < 8; ++i)
#pragma unroll
                for (int j = 0; j < 8; ++j) acc[i][j] = fmaf(a[i], b[j], acc[i][j]);
        }
        __syncthreads();
    }
#pragma unroll
    for (int i = 0; i < 8; ++i) {
        int grow = row0 + ty * 8 + i;
        if (grow < N_NODES) {
            uint4 pk;
            pk.x = (unsigned int)f2bf(acc[i][0]) | ((unsigned int)f2bf(acc[i][1]) << 16);
            pk.y = (unsigned int)f2bf(acc[i][2]) | ((unsigned int)f2bf(acc[i][3]) << 16);
            pk.z = (unsigned int)f2bf(acc[i][4]) | ((unsigned int)f2bf(acc[i][5]) << 16);
            pk.w = (unsigned int)f2bf(acc[i][6]) | ((unsigned int)f2bf(acc[i][7]) << 16);
            *(uint4*)(Cb + (long long)grow * HID_DIM + tx * 8) = pk;
        }
    }
}

// ---------------- layer 1 fused: gather(+bias+self)+ReLU -> GEMM2 -> h2b(bf16) ----------------
// one wave per node; lane handles cols {2*lane, 2*lane+1} of the 128-wide row

__global__ __launch_bounds__(256) void k_layer1(const unsigned short* __restrict__ h1b,
                                                const float* __restrict__ dinv,
                                                const float* __restrict__ b1,
                                                const float* __restrict__ W2,
                                                const int* __restrict__ row_ptr,
                                                const float2* __restrict__ csr,
                                                unsigned short* __restrict__ h2b) {
    __shared__ float W2s[HID_DIM * OUT_DIM];  // 20 KB
    __shared__ float hs[4][HID_DIM];          // 2 KB
    const int tid = threadIdx.x;
    for (int i = tid; i < HID_DIM * OUT_DIM; i += 256) W2s[i] = W2[i];

    const int w    = tid >> 6;
    const int lane = tid & 63;
    const int node = blockIdx.x * 4 + w;  // grid exact: 12500*4
    const float di = dinv[node];
    const int c0 = lane * 2;

    // self-loop + bias
    unsigned int us = *(const unsigned int*)(h1b + (size_t)node * HID_DIM + c0);
    float a0 = fmaf(di * di, bf2f((unsigned short)us), b1[c0]);
    float a1 = fmaf(di * di, bf2f((unsigned short)(us >> 16)), b1[c0 + 1]);

    int j = row_ptr[node];
    const int je = row_ptr[node + 1];
    for (; j + 1 < je; j += 2) {
        float2 e0 = csr[j], e1 = csr[j + 1];
        unsigned int u0 = *(const unsigned int*)(h1b + (size_t)__float_as_int(e0.x) * HID_DIM + c0);
        unsigned int u1 = *(const unsigned int*)(h1b + (size_t)__float_as_int(e1.x) * HID_DIM + c0);
        a0 = fmaf(e0.y, bf2f((unsigned short)u0), a0);
        a1 = fmaf(e0.y, bf2f((unsigned short)(u0 >> 16)), a1);
        a0 = fmaf(e1.y, bf2f((unsigned short)u1), a0);
        a1 = fmaf(e1.y, bf2f((unsigned short)(u1 >> 16)), a1);
    }
    if (j < je) {
        float2 e0 = csr[j];
        unsigned int u0 = *(const unsigned int*)(h1b + (size_t)__float_as_int(e0.x) * HID_DIM + c0);
        a0 = fmaf(e0.y, bf2f((unsigned short)u0), a0);
        a1 = fmaf(e0.y, bf2f((unsigned short)(u0 >> 16)), a1);
    }
    hs[w][c0]     = fmaxf(a0, 0.f);
    hs[w][c0 + 1] = fmaxf(a1, 0.f);
    __syncthreads();

    // fused GEMM2 row: h2[node][c] = dot(hs[w][:], W2[:][c])
    if (lane < OUT_DIM) {
        float acc = 0.f;
#pragma unroll 8
        for (int k = 0; k < HID_DIM; ++k)
            acc = fmaf(hs[w][k], W2s[k * OUT_DIM + lane], acc);
        h2b[(size_t)node * H2_STRIDE + lane] = f2bf(acc);
    }
}

// ---------------- gather layer 2 (+bias+self) + log_softmax -> out ----------------

__global__ __launch_bounds__(256) void k_gather2(const unsigned short* __restrict__ h2b,
                                                 const float* __restrict__ dinv,
                                                 const float* __restrict__ b2,
                                                 const int* __restrict__ row_ptr,
                                                 const float2* __restrict__ csr,
                                                 float* __restrict__ out) {
    const int node = blockIdx.x * 4 + (threadIdx.x >> 6);
    const int lane = threadIdx.x & 63;
    const bool act = lane < OUT_DIM;
    const float di = dinv[node];
    float a = act ? fmaf(di * di, bf2f(h2b[(size_t)node * H2_STRIDE + lane]), b2[lane]) : 0.f;

    int j = row_ptr[node];
    const int je = row_ptr[node + 1];
    for (; j + 1 < je; j += 2) {
        float2 e0 = csr[j], e1 = csr[j + 1];
        if (act) {
            float v0 = bf2f(h2b[(size_t)__float_as_int(e0.x) * H2_STRIDE + lane]);
            float v1 = bf2f(h2b[(size_t)__float_as_int(e1.x) * H2_STRIDE + lane]);
            a = fmaf(e0.y, v0, a);
            a = fmaf(e1.y, v1, a);
        }
    }
    if (j < je) {
        float2 e0 = csr[j];
        if (act) a = fmaf(e0.y, bf2f(h2b[(size_t)__float_as_int(e0.x) * H2_STRIDE + lane]), a);
    }

    // fused row log_softmax over lanes 0..39
    float v = act ? a : -INFINITY;
    float m = v;
#pragma unroll
    for (int off = 32; off > 0; off >>= 1) m = fmaxf(m, __shfl_xor(m, off));
    float ex = act ? expf(v - m) : 0.f;
    float s = ex;
#pragma unroll
    for (int off = 32; off > 0; off >>= 1) s += __shfl_xor(s, off);
    float ls = logf(s);
    if (act) out[(long long)node * OUT_DIM + lane] = v - m - ls;
}

// ---------------- launch ----------------

extern "C" void kernel_launch(void* const* d_in, const int* in_sizes, int n_in,
                              void* d_out, int out_size, void* d_ws, size_t ws_size,
                              hipStream_t stream) {
    const float* x  = (const float*)d_in[0];
    const int*   ei = (const int*)d_in[1];
    const float* W1 = (const float*)d_in[2];
    const float* b1 = (const float*)d_in[3];
    const float* W2 = (const float*)d_in[4];
    const float* b2 = (const float*)d_in[5];
    float* out = (float*)d_out;

    const int* esrc = ei;
    const int* edst = ei + N_EDGES;

    // workspace layout
    char* w = (char*)d_ws;
    int*    count   = (int*)w;      w += sizeof(int) * N_NODES;
    int*    excl    = (int*)w;      w += sizeof(int) * N_NODES;
    int*    partial = (int*)w;      w += sizeof(int) * 64;
    int*    row_ptr = (int*)w;      w += sizeof(int) * (N_NODES + 1);
    w += sizeof(int) * 3;  // align to 16B
    int*    cursor  = (int*)w;      w += sizeof(int) * N_NODES;
    float*  dinv    = (float*)w;    w += sizeof(float) * N_NODES;
    float2* csr     = (float2*)w;   w += sizeof(float2) * N_EDGES;
    unsigned short* h1b = (unsigned short*)w;  w += sizeof(short) * (size_t)N_NODES * HID_DIM;
    unsigned short* h2b = (unsigned short*)w;  w += sizeof(short) * (size_t)N_NODES * H2_STRIDE;

    const int nblk_nodes = (N_NODES + 255) / 256;
    const int nblk_edges = (N_EDGES + 255) / 256;

    // CSR build
    k_zero<<<nblk_nodes, 256, 0, stream>>>(count, N_NODES);
    k_count<<<nblk_edges, 256, 0, stream>>>(edst, count);
    k_scan1<<<N_SCAN_BLKS, 256, 0, stream>>>(count, excl, partial);
    k_scan2<<<1, 64, 0, stream>>>(partial);
    k_scan3<<<nblk_nodes, 256, 0, stream>>>(count, excl, partial, row_ptr, cursor, dinv);
    k_fill<<<nblk_edges, 256, 0, stream>>>(esrc, edst, dinv, cursor, csr);

    // layer 1: GEMM (f32 in, bf16 out)
    k_gemm1<<<(N_NODES + 127) / 128, 256, 0, stream>>>(x, W1, h1b);

    // fused gather1 + ReLU + GEMM2
    k_layer1<<<N_NODES / 4, 256, 0, stream>>>(h1b, dinv, b1, W2, row_ptr, csr, h2b);

    // gather2 + log_softmax
    k_gather2<<<N_NODES / 4, 256, 0, stream>>>(h2b, dinv, b2, row_ptr, csr, out);
}

// Round 4
// 376.005 us; speedup vs baseline: 3.1036x; 1.1975x over previous
//
#include <hip/hip_runtime.h>
#include <math.h>

#define N_NODES 50000
#define N_EDGES 1600000
#define IN_DIM 256
#define HID_DIM 128
#define OUT_DIM 40
#define H2_STRIDE 64
#define SCAN_BLK 1024
#define N_SCAN_BLKS ((N_NODES + SCAN_BLK - 1) / SCAN_BLK)  // 49

typedef __attribute__((ext_vector_type(8))) short bf16x8;
typedef __attribute__((ext_vector_type(4))) float f32x4;

// ---------------- bf16 helpers (RNE) ----------------
__device__ __forceinline__ unsigned int f2bf(float f) {
    unsigned int u = __float_as_uint(f);
    unsigned int r = u + 0x7FFFu + ((u >> 16) & 1u);
    return r >> 16;
}
__device__ __forceinline__ float bf2f(unsigned short s) {
    return __uint_as_float(((unsigned int)s) << 16);
}

// ---------------- CSR build ----------------

__global__ void k_zero(int* __restrict__ p, int n) {
    int i = blockIdx.x * 256 + threadIdx.x;
    if (i < n) p[i] = 0;
}

__global__ void k_count(const int* __restrict__ dst, int* __restrict__ count) {
    int e = blockIdx.x * 256 + threadIdx.x;
    if (e < N_EDGES) atomicAdd(&count[dst[e]], 1);
}

__global__ __launch_bounds__(256) void k_scan1(const int* __restrict__ count,
                                               int* __restrict__ excl,
                                               int* __restrict__ partial) {
    __shared__ int sh[256];
    const int tid = threadIdx.x;
    const int base = blockIdx.x * SCAN_BLK + tid * 4;
    int v[4], sum = 0;
#pragma unroll
    for (int j = 0; j < 4; ++j) {
        v[j] = (base + j < N_NODES) ? count[base + j] : 0;
        sum += v[j];
    }
    sh[tid] = sum;
    __syncthreads();
    for (int off = 1; off < 256; off <<= 1) {
        int t = (tid >= off) ? sh[tid - off] : 0;
        __syncthreads();
        sh[tid] += t;
        __syncthreads();
    }
    int run = sh[tid] - sum;
#pragma unroll
    for (int j = 0; j < 4; ++j) {
        if (base + j < N_NODES) excl[base + j] = run;
        run += v[j];
    }
    if (tid == 255) partial[blockIdx.x] = sh[255];
}

__global__ void k_scan2(int* __restrict__ partial) {
    if (threadIdx.x == 0) {
        int run = 0;
        for (int i = 0; i < N_SCAN_BLKS; ++i) {
            int v = partial[i];
            partial[i] = run;
            run += v;
        }
    }
}

__global__ void k_scan3(const int* __restrict__ count, const int* __restrict__ excl,
                        const int* __restrict__ partial, int* __restrict__ row_ptr,
                        int* __restrict__ cursor, float* __restrict__ dinv) {
    int i = blockIdx.x * 256 + threadIdx.x;
    if (i < N_NODES) {
        int rp = excl[i] + partial[i >> 10];
        row_ptr[i] = rp;
        cursor[i] = rp;
        dinv[i] = rsqrtf((float)count[i] + 1.0f);
    }
    if (i == 0) row_ptr[N_NODES] = N_EDGES;
}

__global__ void k_fill(const int* __restrict__ src, const int* __restrict__ dst,
                       const float* __restrict__ dinv, int* __restrict__ cursor,
                       float2* __restrict__ csr) {
    int e = blockIdx.x * 256 + threadIdx.x;
    if (e >= N_EDGES) return;
    int s = src[e], d = dst[e];
    int pos = atomicAdd(&cursor[d], 1);
    csr[pos] = make_float2(__int_as_float(s), dinv[s] * dinv[d]);
}

// ---------------- W1^T bf16 [128][256] ----------------
__global__ __launch_bounds__(256) void k_w1t(const float* __restrict__ W1,
                                             unsigned short* __restrict__ w1t) {
    int c = blockIdx.x;        // 0..127 output row (= W1 col)
    int k = threadIdx.x;       // 0..255
    w1t[c * IN_DIM + k] = (unsigned short)f2bf(W1[k * HID_DIM + c]);
}

// ---------------- GEMM1 (MFMA): h1b[N][128](bf16) = x @ W1 ----------------
// 64x128 tile per block (4 waves, each 16 rows x 128 cols), BK=32

__global__ __launch_bounds__(256) void k_gemm1_mfma(const float* __restrict__ x,
                                                    const unsigned short* __restrict__ w1t,
                                                    unsigned short* __restrict__ h1b) {
    __shared__ unsigned short Asub[64 * 32];   // [row][k], 16B slots XOR-swizzled by row&3
    __shared__ unsigned short Bsub[128 * 32];  // [col][k], 16B slots XOR-swizzled by col&3
    const int tid  = threadIdx.x;
    const int w    = tid >> 6;
    const int lane = tid & 63;
    const int row0 = blockIdx.x * 64;
    const int r  = lane & 15;
    const int kg = lane >> 4;

    f32x4 acc[8] = {};

    for (int k0 = 0; k0 < IN_DIM; k0 += 32) {
        // ---- stage A (f32 -> bf16 inline): 64 rows x 32 k ----
        {
            int ar = tid >> 2, as = tid & 3;
            int asw = as ^ (ar & 3);
            uint4 pk = make_uint4(0, 0, 0, 0);
            int grow = row0 + ar;
            if (grow < N_NODES) {
                const float4* p = (const float4*)(x + (size_t)grow * IN_DIM + k0 + as * 8);
                float4 v0 = p[0], v1 = p[1];
                pk.x = f2bf(v0.x) | (f2bf(v0.y) << 16);
                pk.y = f2bf(v0.z) | (f2bf(v0.w) << 16);
                pk.z = f2bf(v1.x) | (f2bf(v1.y) << 16);
                pk.w = f2bf(v1.z) | (f2bf(v1.w) << 16);
            }
            *(uint4*)(Asub + ar * 32 + asw * 8) = pk;
        }
        // ---- stage B: 128 cols x 32 k from w1t (already [col][k]) ----
#pragma unroll
        for (int i = 0; i < 2; ++i) {
            int q = tid + i * 256;           // 0..511 16B-chunks
            int col = q >> 2, slot = q & 3;
            int sl2 = slot ^ (col & 3);
            *(uint4*)(Bsub + col * 32 + sl2 * 8) =
                *(const uint4*)(w1t + (size_t)col * IN_DIM + k0 + slot * 8);
        }
        __syncthreads();

        bf16x8 af = *(const bf16x8*)(Asub + (w * 16 + r) * 32 + ((kg ^ (r & 3)) * 8));
#pragma unroll
        for (int f = 0; f < 8; ++f) {
            bf16x8 bfr = *(const bf16x8*)(Bsub + (f * 16 + r) * 32 + ((kg ^ (r & 3)) * 8));
            acc[f] = __builtin_amdgcn_mfma_f32_16x16x32_bf16(af, bfr, acc[f], 0, 0, 0);
        }
        __syncthreads();
    }

    // D layout: col = lane&15, row = (lane>>4)*4 + v  [m89-verified]
#pragma unroll
    for (int f = 0; f < 8; ++f)
#pragma unroll
        for (int v = 0; v < 4; ++v) {
            int gr = row0 + w * 16 + kg * 4 + v;
            if (gr < N_NODES)
                h1b[(size_t)gr * HID_DIM + f * 16 + r] = (unsigned short)f2bf(acc[f][v]);
        }
}

// ---------------- layer 1 fused: gather(+bias+self)+ReLU -> GEMM2 -> h2b(bf16) ----------------
// one wave per node, unroll-8 gathers for MLP; grid-stride so W2 stages once per block

__global__ __launch_bounds__(256) void k_layer1(const unsigned short* __restrict__ h1b,
                                                const float* __restrict__ dinv,
                                                const float* __restrict__ b1,
                                                const float* __restrict__ W2,
                                                const int* __restrict__ row_ptr,
                                                const float2* __restrict__ csr,
                                                unsigned short* __restrict__ h2b) {
    __shared__ float W2s[HID_DIM * OUT_DIM];  // 20 KB
    __shared__ float hs[4][HID_DIM];          // wave-private rows
    const int tid = threadIdx.x;
    for (int i = tid; i < HID_DIM * OUT_DIM; i += 256) W2s[i] = W2[i];
    __syncthreads();  // W2s ready; hs is wave-private (per-wave DS ordering suffices)

    const int w    = tid >> 6;
    const int lane = tid & 63;
    const int c0   = lane * 2;

    for (int g = blockIdx.x; g < N_NODES / 4; g += gridDim.x) {
        const int node = g * 4 + w;
        const float di = dinv[node];

        unsigned int us = *(const unsigned int*)(h1b + (size_t)node * HID_DIM + c0);
        float a0 = fmaf(di * di, bf2f((unsigned short)us), b1[c0]);
        float a1 = fmaf(di * di, bf2f((unsigned short)(us >> 16)), b1[c0 + 1]);

        int j = row_ptr[node];
        const int je = row_ptr[node + 1];
        for (; j + 8 <= je; j += 8) {
            float2 e[8];
#pragma unroll
            for (int u = 0; u < 8; ++u) e[u] = csr[j + u];
            unsigned int uu[8];
#pragma unroll
            for (int u = 0; u < 8; ++u)
                uu[u] = *(const unsigned int*)(h1b + (size_t)__float_as_int(e[u].x) * HID_DIM + c0);
#pragma unroll
            for (int u = 0; u < 8; ++u) {
                a0 = fmaf(e[u].y, bf2f((unsigned short)uu[u]), a0);
                a1 = fmaf(e[u].y, bf2f((unsigned short)(uu[u] >> 16)), a1);
            }
        }
        if (j + 4 <= je) {
            float2 e[4];
#pragma unroll
            for (int u = 0; u < 4; ++u) e[u] = csr[j + u];
            unsigned int uu[4];
#pragma unroll
            for (int u = 0; u < 4; ++u)
                uu[u] = *(const unsigned int*)(h1b + (size_t)__float_as_int(e[u].x) * HID_DIM + c0);
#pragma unroll
            for (int u = 0; u < 4; ++u) {
                a0 = fmaf(e[u].y, bf2f((unsigned short)uu[u]), a0);
                a1 = fmaf(e[u].y, bf2f((unsigned short)(uu[u] >> 16)), a1);
            }
            j += 4;
        }
        for (; j < je; ++j) {
            float2 e0 = csr[j];
            unsigned int u0 = *(const unsigned int*)(h1b + (size_t)__float_as_int(e0.x) * HID_DIM + c0);
            a0 = fmaf(e0.y, bf2f((unsigned short)u0), a0);
            a1 = fmaf(e0.y, bf2f((unsigned short)(u0 >> 16)), a1);
        }

        hs[w][c0]     = fmaxf(a0, 0.f);
        hs[w][c0 + 1] = fmaxf(a1, 0.f);
        // no barrier: hs[w] written and read only by wave w; DS ops are in-order per wave

        if (lane < OUT_DIM) {
            float acc = 0.f;
#pragma unroll 8
            for (int k = 0; k < HID_DIM; ++k)
                acc = fmaf(hs[w][k], W2s[k * OUT_DIM + lane], acc);
            h2b[(size_t)node * H2_STRIDE + lane] = (unsigned short)f2bf(acc);
        }
    }
}

// ---------------- gather layer 2 (+bias+self) + log_softmax -> out ----------------

__global__ __launch_bounds__(256) void k_gather2(const unsigned short* __restrict__ h2b,
                                                 const float* __restrict__ dinv,
                                                 const float* __restrict__ b2,
                                                 const int* __restrict__ row_ptr,
                                                 const float2* __restrict__ csr,
                                                 float* __restrict__ out) {
    const int node = blockIdx.x * 4 + (threadIdx.x >> 6);
    const int lane = threadIdx.x & 63;
    const bool act = lane < OUT_DIM;
    const float di = dinv[node];
    float a = act ? fmaf(di * di, bf2f(h2b[(size_t)node * H2_STRIDE + lane]), b2[lane]) : 0.f;

    int j = row_ptr[node];
    const int je = row_ptr[node + 1];
    for (; j + 8 <= je; j += 8) {
        float2 e[8];
#pragma unroll
        for (int u = 0; u < 8; ++u) e[u] = csr[j + u];
        unsigned short hv[8];
#pragma unroll
        for (int u = 0; u < 8; ++u)
            hv[u] = act ? h2b[(size_t)__float_as_int(e[u].x) * H2_STRIDE + lane] : 0;
#pragma unroll
        for (int u = 0; u < 8; ++u)
            if (act) a = fmaf(e[u].y, bf2f(hv[u]), a);
    }
    if (j + 4 <= je) {
        float2 e[4];
#pragma unroll
        for (int u = 0; u < 4; ++u) e[u] = csr[j + u];
        unsigned short hv[4];
#pragma unroll
        for (int u = 0; u < 4; ++u)
            hv[u] = act ? h2b[(size_t)__float_as_int(e[u].x) * H2_STRIDE + lane] : 0;
#pragma unroll
        for (int u = 0; u < 4; ++u)
            if (act) a = fmaf(e[u].y, bf2f(hv[u]), a);
        j += 4;
    }
    for (; j < je; ++j) {
        float2 e0 = csr[j];
        if (act) a = fmaf(e0.y, bf2f(h2b[(size_t)__float_as_int(e0.x) * H2_STRIDE + lane]), a);
    }

    float v = act ? a : -INFINITY;
    float m = v;
#pragma unroll
    for (int off = 32; off > 0; off >>= 1) m = fmaxf(m, __shfl_xor(m, off));
    float ex = act ? expf(v - m) : 0.f;
    float s = ex;
#pragma unroll
    for (int off = 32; off > 0; off >>= 1) s += __shfl_xor(s, off);
    float ls = logf(s);
    if (act) out[(long long)node * OUT_DIM + lane] = v - m - ls;
}

// ---------------- launch ----------------

extern "C" void kernel_launch(void* const* d_in, const int* in_sizes, int n_in,
                              void* d_out, int out_size, void* d_ws, size_t ws_size,
                              hipStream_t stream) {
    const float* x  = (const float*)d_in[0];
    const int*   ei = (const int*)d_in[1];
    const float* W1 = (const float*)d_in[2];
    const float* b1 = (const float*)d_in[3];
    const float* W2 = (const float*)d_in[4];
    const float* b2 = (const float*)d_in[5];
    float* out = (float*)d_out;

    const int* esrc = ei;
    const int* edst = ei + N_EDGES;

    char* w = (char*)d_ws;
    int*    count   = (int*)w;      w += sizeof(int) * N_NODES;
    int*    excl    = (int*)w;      w += sizeof(int) * N_NODES;
    int*    partial = (int*)w;      w += sizeof(int) * 64;
    int*    row_ptr = (int*)w;      w += sizeof(int) * (N_NODES + 1);
    w += sizeof(int) * 3;  // 16B align
    int*    cursor  = (int*)w;      w += sizeof(int) * N_NODES;
    float*  dinv    = (float*)w;    w += sizeof(float) * N_NODES;
    float2* csr     = (float2*)w;   w += sizeof(float2) * N_EDGES;
    unsigned short* h1b = (unsigned short*)w;  w += sizeof(short) * (size_t)N_NODES * HID_DIM;
    unsigned short* h2b = (unsigned short*)w;  w += sizeof(short) * (size_t)N_NODES * H2_STRIDE;
    unsigned short* w1t = (unsigned short*)w;  w += sizeof(short) * HID_DIM * IN_DIM;

    const int nblk_nodes = (N_NODES + 255) / 256;
    const int nblk_edges = (N_EDGES + 255) / 256;

    // CSR build
    k_zero<<<nblk_nodes, 256, 0, stream>>>(count, N_NODES);
    k_count<<<nblk_edges, 256, 0, stream>>>(edst, count);
    k_scan1<<<N_SCAN_BLKS, 256, 0, stream>>>(count, excl, partial);
    k_scan2<<<1, 64, 0, stream>>>(partial);
    k_scan3<<<nblk_nodes, 256, 0, stream>>>(count, excl, partial, row_ptr, cursor, dinv);
    k_fill<<<nblk_edges, 256, 0, stream>>>(esrc, edst, dinv, cursor, csr);

    // layer 1 GEMM via MFMA
    k_w1t<<<HID_DIM, IN_DIM, 0, stream>>>(W1, w1t);
    k_gemm1_mfma<<<(N_NODES + 63) / 64, 256, 0, stream>>>(x, w1t, h1b);

    // fused gather1 + ReLU + GEMM2
    k_layer1<<<2048, 256, 0, stream>>>(h1b, dinv, b1, W2, row_ptr, csr, h2b);

    // gather2 + log_softmax
    k_gather2<<<N_NODES / 4, 256, 0, stream>>>(h2b, dinv, b2, row_ptr, csr, out);
}

// Round 5
// 373.982 us; speedup vs baseline: 3.1204x; 1.0054x over previous
//
#include <hip/hip_runtime.h>
#include <math.h>

#define N_NODES 50000
#define N_EDGES 1600000
#define IN_DIM 256
#define HID_DIM 128
#define OUT_DIM 40
#define H2_STRIDE 64
#define SCAN_BLK 1024
#define N_SCAN_BLKS ((N_NODES + SCAN_BLK - 1) / SCAN_BLK)  // 49

typedef __attribute__((ext_vector_type(8))) short bf16x8;
typedef __attribute__((ext_vector_type(4))) float f32x4;

// ---------------- bf16 helpers (RNE) ----------------
__device__ __forceinline__ unsigned int f2bf(float f) {
    unsigned int u = __float_as_uint(f);
    unsigned int r = u + 0x7FFFu + ((u >> 16) & 1u);
    return r >> 16;
}
__device__ __forceinline__ float bf2f(unsigned short s) {
    return __uint_as_float(((unsigned int)s) << 16);
}

// ---------------- CSR build ----------------

__global__ void k_zero(int* __restrict__ p, int n) {
    int i = blockIdx.x * 256 + threadIdx.x;
    if (i < n) p[i] = 0;
}

// 4 edges per thread: independent atomics in flight
__global__ void k_count(const int* __restrict__ dst, int* __restrict__ count) {
    int e = (blockIdx.x * 256 + threadIdx.x) * 4;
    if (e + 4 <= N_EDGES) {
        int4 d = *(const int4*)(dst + e);
        atomicAdd(&count[d.x], 1);
        atomicAdd(&count[d.y], 1);
        atomicAdd(&count[d.z], 1);
        atomicAdd(&count[d.w], 1);
    } else {
        for (; e < N_EDGES; ++e) atomicAdd(&count[dst[e]], 1);
    }
}

__global__ __launch_bounds__(256) void k_scan1(const int* __restrict__ count,
                                               int* __restrict__ excl,
                                               int* __restrict__ partial) {
    __shared__ int sh[256];
    const int tid = threadIdx.x;
    const int base = blockIdx.x * SCAN_BLK + tid * 4;
    int v[4], sum = 0;
#pragma unroll
    for (int j = 0; j < 4; ++j) {
        v[j] = (base + j < N_NODES) ? count[base + j] : 0;
        sum += v[j];
    }
    sh[tid] = sum;
    __syncthreads();
    for (int off = 1; off < 256; off <<= 1) {
        int t = (tid >= off) ? sh[tid - off] : 0;
        __syncthreads();
        sh[tid] += t;
        __syncthreads();
    }
    int run = sh[tid] - sum;
#pragma unroll
    for (int j = 0; j < 4; ++j) {
        if (base + j < N_NODES) excl[base + j] = run;
        run += v[j];
    }
    if (tid == 255) partial[blockIdx.x] = sh[255];
}

__global__ void k_scan2(int* __restrict__ partial) {
    if (threadIdx.x == 0) {
        int run = 0;
        for (int i = 0; i < N_SCAN_BLKS; ++i) {
            int v = partial[i];
            partial[i] = run;
            run += v;
        }
    }
}

__global__ void k_scan3(const int* __restrict__ count, const int* __restrict__ excl,
                        const int* __restrict__ partial, int* __restrict__ row_ptr,
                        int* __restrict__ cursor, float* __restrict__ dinv) {
    int i = blockIdx.x * 256 + threadIdx.x;
    if (i < N_NODES) {
        int rp = excl[i] + partial[i >> 10];
        row_ptr[i] = rp;
        cursor[i] = rp;
        dinv[i] = rsqrtf((float)count[i] + 1.0f);
    }
    if (i == 0) row_ptr[N_NODES] = N_EDGES;
}

// 4 edges per thread; csr entry = src index only (4B)
__global__ void k_fill(const int* __restrict__ src, const int* __restrict__ dst,
                       int* __restrict__ cursor, int* __restrict__ csr) {
    int e = (blockIdx.x * 256 + threadIdx.x) * 4;
    if (e + 4 <= N_EDGES) {
        int4 s = *(const int4*)(src + e);
        int4 d = *(const int4*)(dst + e);
        int p0 = atomicAdd(&cursor[d.x], 1);
        int p1 = atomicAdd(&cursor[d.y], 1);
        int p2 = atomicAdd(&cursor[d.z], 1);
        int p3 = atomicAdd(&cursor[d.w], 1);
        csr[p0] = s.x;
        csr[p1] = s.y;
        csr[p2] = s.z;
        csr[p3] = s.w;
    } else {
        for (; e < N_EDGES; ++e) {
            int pos = atomicAdd(&cursor[dst[e]], 1);
            csr[pos] = src[e];
        }
    }
}

// ---------------- W1^T bf16 [128][256] ----------------
__global__ __launch_bounds__(256) void k_w1t(const float* __restrict__ W1,
                                             unsigned short* __restrict__ w1t) {
    int c = blockIdx.x;
    int k = threadIdx.x;
    w1t[c * IN_DIM + k] = (unsigned short)f2bf(W1[k * HID_DIM + c]);
}

// ---------------- GEMM1 (MFMA): h1b[N][128](bf16) = dinv * (x @ W1) ----------------

__global__ __launch_bounds__(256) void k_gemm1_mfma(const float* __restrict__ x,
                                                    const unsigned short* __restrict__ w1t,
                                                    const float* __restrict__ dinv,
                                                    unsigned short* __restrict__ h1b) {
    __shared__ unsigned short Asub[64 * 32];
    __shared__ unsigned short Bsub[128 * 32];
    const int tid  = threadIdx.x;
    const int w    = tid >> 6;
    const int lane = tid & 63;
    const int row0 = blockIdx.x * 64;
    const int r  = lane & 15;
    const int kg = lane >> 4;

    f32x4 acc[8] = {};

    for (int k0 = 0; k0 < IN_DIM; k0 += 32) {
        {
            int ar = tid >> 2, as = tid & 3;
            int asw = as ^ (ar & 3);
            uint4 pk = make_uint4(0, 0, 0, 0);
            int grow = row0 + ar;
            if (grow < N_NODES) {
                const float4* p = (const float4*)(x + (size_t)grow * IN_DIM + k0 + as * 8);
                float4 v0 = p[0], v1 = p[1];
                pk.x = f2bf(v0.x) | (f2bf(v0.y) << 16);
                pk.y = f2bf(v0.z) | (f2bf(v0.w) << 16);
                pk.z = f2bf(v1.x) | (f2bf(v1.y) << 16);
                pk.w = f2bf(v1.z) | (f2bf(v1.w) << 16);
            }
            *(uint4*)(Asub + ar * 32 + asw * 8) = pk;
        }
#pragma unroll
        for (int i = 0; i < 2; ++i) {
            int q = tid + i * 256;
            int col = q >> 2, slot = q & 3;
            int sl2 = slot ^ (col & 3);
            *(uint4*)(Bsub + col * 32 + sl2 * 8) =
                *(const uint4*)(w1t + (size_t)col * IN_DIM + k0 + slot * 8);
        }
        __syncthreads();

        bf16x8 af = *(const bf16x8*)(Asub + (w * 16 + r) * 32 + ((kg ^ (r & 3)) * 8));
#pragma unroll
        for (int f = 0; f < 8; ++f) {
            bf16x8 bfr = *(const bf16x8*)(Bsub + (f * 16 + r) * 32 + ((kg ^ (r & 3)) * 8));
            acc[f] = __builtin_amdgcn_mfma_f32_16x16x32_bf16(af, bfr, acc[f], 0, 0, 0);
        }
        __syncthreads();
    }

    // D layout: col = lane&15, row = (lane>>4)*4 + v
    float dv[4];
#pragma unroll
    for (int v = 0; v < 4; ++v) {
        int gr = row0 + w * 16 + kg * 4 + v;
        dv[v] = (gr < N_NODES) ? dinv[gr] : 0.f;
    }
#pragma unroll
    for (int f = 0; f < 8; ++f)
#pragma unroll
        for (int v = 0; v < 4; ++v) {
            int gr = row0 + w * 16 + kg * 4 + v;
            if (gr < N_NODES)
                h1b[(size_t)gr * HID_DIM + f * 16 + r] = (unsigned short)f2bf(acc[f][v] * dv[v]);
        }
}

// ---------------- layer 1 fused: pure-sum gather -> scale+bias+ReLU -> GEMM2 -> h2b' ----------------

__global__ __launch_bounds__(256) void k_layer1(const unsigned short* __restrict__ h1b,
                                                const float* __restrict__ dinv,
                                                const float* __restrict__ b1,
                                                const float* __restrict__ W2,
                                                const int* __restrict__ row_ptr,
                                                const int* __restrict__ csr,
                                                unsigned short* __restrict__ h2b) {
    __shared__ float W2s[HID_DIM * OUT_DIM];  // 20 KB
    __shared__ float hs[4][HID_DIM];
    const int tid = threadIdx.x;
    for (int i = tid; i < HID_DIM * OUT_DIM; i += 256) W2s[i] = W2[i];
    __syncthreads();

    const int w    = tid >> 6;
    const int lane = tid & 63;
    const int c0   = lane * 2;

    for (int g = blockIdx.x; g < N_NODES / 4; g += gridDim.x) {
        const int node = g * 4 + w;
        const float di = dinv[node];

        // self term: h1b is pre-scaled by dinv[src]
        unsigned int us = *(const unsigned int*)(h1b + (size_t)node * HID_DIM + c0);
        float a0 = bf2f((unsigned short)us);
        float a1 = bf2f((unsigned short)(us >> 16));

        const int jb = row_ptr[node];
        const int je = row_ptr[node + 1];
        for (int j = jb; j < je; j += 8) {
            int idx[8];
#pragma unroll
            for (int u = 0; u < 8; ++u) {
                int jj = j + u;
                idx[u] = csr[jj < je ? jj : je - 1];
            }
            unsigned int uu[8];
#pragma unroll
            for (int u = 0; u < 8; ++u)
                uu[u] = *(const unsigned int*)(h1b + (size_t)idx[u] * HID_DIM + c0);
#pragma unroll
            for (int u = 0; u < 8; ++u) {
                bool ok = (j + u) < je;
                a0 += ok ? bf2f((unsigned short)uu[u]) : 0.f;
                a1 += ok ? bf2f((unsigned short)(uu[u] >> 16)) : 0.f;
            }
        }

        hs[w][c0]     = fmaxf(fmaf(di, a0, b1[c0]), 0.f);
        hs[w][c0 + 1] = fmaxf(fmaf(di, a1, b1[c0 + 1]), 0.f);
        // hs[w] is wave-private; per-wave DS ordering suffices

        if (lane < OUT_DIM) {
            float acc = 0.f;
#pragma unroll 8
            for (int k = 0; k < HID_DIM; ++k)
                acc = fmaf(hs[w][k], W2s[k * OUT_DIM + lane], acc);
            h2b[(size_t)node * H2_STRIDE + lane] = (unsigned short)f2bf(acc * di);  // pre-scale for layer-2 gather
        }
    }
}

// ---------------- gather layer 2 (pure sum) + bias + log_softmax -> out ----------------

__global__ __launch_bounds__(256) void k_gather2(const unsigned short* __restrict__ h2b,
                                                 const float* __restrict__ dinv,
                                                 const float* __restrict__ b2,
                                                 const int* __restrict__ row_ptr,
                                                 const int* __restrict__ csr,
                                                 float* __restrict__ out) {
    const int node = blockIdx.x * 4 + (threadIdx.x >> 6);
    const int lane = threadIdx.x & 63;
    const bool act = lane < OUT_DIM;
    const float di = dinv[node];

    float a = bf2f(h2b[(size_t)node * H2_STRIDE + lane]);  // self (pre-scaled); pad lanes read garbage, masked later

    const int jb = row_ptr[node];
    const int je = row_ptr[node + 1];
    for (int j = jb; j < je; j += 8) {
        int idx[8];
#pragma unroll
        for (int u = 0; u < 8; ++u) {
            int jj = j + u;
            idx[u] = csr[jj < je ? jj : je - 1];
        }
        unsigned short hv[8];
#pragma unroll
        for (int u = 0; u < 8; ++u)
            hv[u] = h2b[(size_t)idx[u] * H2_STRIDE + lane];
#pragma unroll
        for (int u = 0; u < 8; ++u)
            a += ((j + u) < je) ? bf2f(hv[u]) : 0.f;
    }

    float v = act ? fmaf(di, a, b2[lane & 31] /*safe idx*/) : -INFINITY;
    // note: lane<OUT_DIM<=40 so b2[lane] valid when act; avoid OOB for lane>=40:
    if (act) v = fmaf(di, a, b2[lane]);

    float m = v;
#pragma unroll
    for (int off = 32; off > 0; off >>= 1) m = fmaxf(m, __shfl_xor(m, off));
    float ex = act ? expf(v - m) : 0.f;
    float s = ex;
#pragma unroll
    for (int off = 32; off > 0; off >>= 1) s += __shfl_xor(s, off);
    float ls = logf(s);
    if (act) out[(long long)node * OUT_DIM + lane] = v - m - ls;
}

// ---------------- launch ----------------

extern "C" void kernel_launch(void* const* d_in, const int* in_sizes, int n_in,
                              void* d_out, int out_size, void* d_ws, size_t ws_size,
                              hipStream_t stream) {
    const float* x  = (const float*)d_in[0];
    const int*   ei = (const int*)d_in[1];
    const float* W1 = (const float*)d_in[2];
    const float* b1 = (const float*)d_in[3];
    const float* W2 = (const float*)d_in[4];
    const float* b2 = (const float*)d_in[5];
    float* out = (float*)d_out;

    const int* esrc = ei;
    const int* edst = ei + N_EDGES;

    char* w = (char*)d_ws;
    int*    count   = (int*)w;      w += sizeof(int) * N_NODES;
    int*    excl    = (int*)w;      w += sizeof(int) * N_NODES;
    int*    partial = (int*)w;      w += sizeof(int) * 64;
    int*    row_ptr = (int*)w;      w += sizeof(int) * (N_NODES + 1);
    w += sizeof(int) * 3;  // 16B align
    int*    cursor  = (int*)w;      w += sizeof(int) * N_NODES;
    float*  dinv    = (float*)w;    w += sizeof(float) * N_NODES;
    int*    csr     = (int*)w;      w += sizeof(int) * N_EDGES;
    unsigned short* h1b = (unsigned short*)w;  w += sizeof(short) * (size_t)N_NODES * HID_DIM;
    unsigned short* h2b = (unsigned short*)w;  w += sizeof(short) * (size_t)N_NODES * H2_STRIDE;
    unsigned short* w1t = (unsigned short*)w;  w += sizeof(short) * HID_DIM * IN_DIM;

    const int nblk_nodes = (N_NODES + 255) / 256;
    const int nblk_e4    = (N_EDGES / 4 + 255) / 256;

    // CSR build
    k_zero<<<nblk_nodes, 256, 0, stream>>>(count, N_NODES);
    k_count<<<nblk_e4, 256, 0, stream>>>(edst, count);
    k_scan1<<<N_SCAN_BLKS, 256, 0, stream>>>(count, excl, partial);
    k_scan2<<<1, 64, 0, stream>>>(partial);
    k_scan3<<<nblk_nodes, 256, 0, stream>>>(count, excl, partial, row_ptr, cursor, dinv);
    k_fill<<<nblk_e4, 256, 0, stream>>>(esrc, edst, cursor, csr);

    // layer 1 GEMM via MFMA (pre-scaled by dinv)
    k_w1t<<<HID_DIM, IN_DIM, 0, stream>>>(W1, w1t);
    k_gemm1_mfma<<<(N_NODES + 63) / 64, 256, 0, stream>>>(x, w1t, dinv, h1b);

    // fused gather1 + ReLU + GEMM2
    k_layer1<<<2048, 256, 0, stream>>>(h1b, dinv, b1, W2, row_ptr, csr, h2b);

    // gather2 + log_softmax
    k_gather2<<<N_NODES / 4, 256, 0, stream>>>(h2b, dinv, b2, row_ptr, csr, out);
}

// Round 6
// 215.905 us; speedup vs baseline: 5.4050x; 1.7322x over previous
//
#include <hip/hip_runtime.h>
#include <math.h>

#define N_NODES 50000
#define N_EDGES 1600000
#define IN_DIM 256
#define HID_DIM 128
#define OUT_DIM 40
#define H2_STRIDE 64

#define NB 196        // dst buckets of 256 nodes (196*256 = 50176 >= 50000)
#define BCAP 16384    // part[] slots per bucket (avg fill ~8163, sigma ~90)
#define PCHUNK 8192   // edges per k_part block
#define NPB ((N_EDGES + PCHUNK - 1) / PCHUNK)  // 196

typedef __attribute__((ext_vector_type(8))) short bf16x8;
typedef __attribute__((ext_vector_type(4))) float f32x4;

// ---------------- bf16 helpers (RNE) ----------------
__device__ __forceinline__ unsigned int f2bf(float f) {
    unsigned int u = __float_as_uint(f);
    unsigned int r = u + 0x7FFFu + ((u >> 16) & 1u);
    return r >> 16;
}
__device__ __forceinline__ float bf2f(unsigned short s) {
    return __uint_as_float(((unsigned int)s) << 16);
}

// ---------------- CSR build: bucket partition + per-bucket counting sort ----------------

__global__ void k_initcur(int* __restrict__ gcursor) {
    int i = threadIdx.x;
    if (i < NB) gcursor[i] = i * BCAP;
}

// 196 blocks x 8192 edges: LDS bucket histogram -> reserve runs -> bin pairs
__global__ __launch_bounds__(256) void k_part(const int* __restrict__ src,
                                              const int* __restrict__ dst,
                                              int* __restrict__ gcursor,
                                              int2* __restrict__ part) {
    __shared__ int hist[NB];
    __shared__ int lcur[NB];
    const int tid = threadIdx.x;
    const int base = blockIdx.x * PCHUNK;
    const int n = min(PCHUNK, N_EDGES - base);

    for (int i = tid; i < NB; i += 256) hist[i] = 0;
    __syncthreads();
    for (int i = tid; i < n; i += 256)
        atomicAdd(&hist[dst[base + i] >> 8], 1);
    __syncthreads();
    for (int i = tid; i < NB; i += 256)
        lcur[i] = atomicAdd(&gcursor[i], hist[i]);  // run base for this block
    __syncthreads();
    for (int i = tid; i < n; i += 256) {
        int d = dst[base + i];
        int g = d >> 8;
        int pos = atomicAdd(&lcur[g], 1);
        part[pos] = make_int2(src[base + i], d);
    }
}

// 1 block: exclusive scan of bucket totals -> bucket_base[0..NB]
__global__ __launch_bounds__(256) void k_bscan(const int* __restrict__ gcursor,
                                               int* __restrict__ bucket_base,
                                               int* __restrict__ row_ptr) {
    __shared__ int sh[256];
    const int tid = threadIdx.x;
    int v = (tid < NB) ? (gcursor[tid] - tid * BCAP) : 0;
    sh[tid] = v;
    __syncthreads();
    for (int off = 1; off < 256; off <<= 1) {
        int t = (tid >= off) ? sh[tid - off] : 0;
        __syncthreads();
        sh[tid] += t;
        __syncthreads();
    }
    if (tid < NB) bucket_base[tid + 1] = sh[tid];
    if (tid == 0) {
        bucket_base[0] = 0;
        row_ptr[N_NODES] = N_EDGES;
    }
}

// 1 block per bucket: local histogram -> row_ptr/dinv, rank-scatter src into 32KB csr segment
__global__ __launch_bounds__(256) void k_bucket(const int2* __restrict__ part,
                                                const int* __restrict__ bucket_base,
                                                int* __restrict__ row_ptr,
                                                float* __restrict__ dinv,
                                                int* __restrict__ csr) {
    __shared__ int hist[256];
    __shared__ int sh[256];
    __shared__ int cur[256];
    const int g = blockIdx.x;
    const int tid = threadIdx.x;
    const int ebase = g * BCAP;
    const int cbase = bucket_base[g];
    const int ecnt = bucket_base[g + 1] - cbase;

    hist[tid] = 0;
    __syncthreads();
    for (int i = tid; i < ecnt; i += 256)
        atomicAdd(&hist[part[ebase + i].y & 255], 1);
    __syncthreads();

    int own = hist[tid];
    sh[tid] = own;
    __syncthreads();
    for (int off = 1; off < 256; off <<= 1) {
        int t = (tid >= off) ? sh[tid - off] : 0;
        __syncthreads();
        sh[tid] += t;
        __syncthreads();
    }
    int excl = sh[tid] - own;

    int node = (g << 8) + tid;
    if (node < N_NODES) {
        row_ptr[node] = cbase + excl;
        dinv[node] = rsqrtf((float)own + 1.0f);  // +1 self-loop
    }
    cur[tid] = cbase + excl;
    __syncthreads();

    for (int i = tid; i < ecnt; i += 256) {
        int2 p = part[ebase + i];
        int pos = atomicAdd(&cur[p.y & 255], 1);
        csr[pos] = p.x;
    }
}

// ---------------- W1^T bf16 [128][256] ----------------
__global__ __launch_bounds__(256) void k_w1t(const float* __restrict__ W1,
                                             unsigned short* __restrict__ w1t) {
    int c = blockIdx.x;
    int k = threadIdx.x;
    w1t[c * IN_DIM + k] = (unsigned short)f2bf(W1[k * HID_DIM + c]);
}

// ---------------- GEMM1 (MFMA): h1b[N][128](bf16) = dinv * (x @ W1) ----------------

__global__ __launch_bounds__(256) void k_gemm1_mfma(const float* __restrict__ x,
                                                    const unsigned short* __restrict__ w1t,
                                                    const float* __restrict__ dinv,
                                                    unsigned short* __restrict__ h1b) {
    __shared__ unsigned short Asub[64 * 32];
    __shared__ unsigned short Bsub[128 * 32];
    const int tid  = threadIdx.x;
    const int w    = tid >> 6;
    const int lane = tid & 63;
    const int row0 = blockIdx.x * 64;
    const int r  = lane & 15;
    const int kg = lane >> 4;

    f32x4 acc[8] = {};

    for (int k0 = 0; k0 < IN_DIM; k0 += 32) {
        {
            int ar = tid >> 2, as = tid & 3;
            int asw = as ^ (ar & 3);
            uint4 pk = make_uint4(0, 0, 0, 0);
            int grow = row0 + ar;
            if (grow < N_NODES) {
                const float4* p = (const float4*)(x + (size_t)grow * IN_DIM + k0 + as * 8);
                float4 v0 = p[0], v1 = p[1];
                pk.x = f2bf(v0.x) | (f2bf(v0.y) << 16);
                pk.y = f2bf(v0.z) | (f2bf(v0.w) << 16);
                pk.z = f2bf(v1.x) | (f2bf(v1.y) << 16);
                pk.w = f2bf(v1.z) | (f2bf(v1.w) << 16);
            }
            *(uint4*)(Asub + ar * 32 + asw * 8) = pk;
        }
#pragma unroll
        for (int i = 0; i < 2; ++i) {
            int q = tid + i * 256;
            int col = q >> 2, slot = q & 3;
            int sl2 = slot ^ (col & 3);
            *(uint4*)(Bsub + col * 32 + sl2 * 8) =
                *(const uint4*)(w1t + (size_t)col * IN_DIM + k0 + slot * 8);
        }
        __syncthreads();

        bf16x8 af = *(const bf16x8*)(Asub + (w * 16 + r) * 32 + ((kg ^ (r & 3)) * 8));
#pragma unroll
        for (int f = 0; f < 8; ++f) {
            bf16x8 bfr = *(const bf16x8*)(Bsub + (f * 16 + r) * 32 + ((kg ^ (r & 3)) * 8));
            acc[f] = __builtin_amdgcn_mfma_f32_16x16x32_bf16(af, bfr, acc[f], 0, 0, 0);
        }
        __syncthreads();
    }

    // D layout: col = lane&15, row = (lane>>4)*4 + v
    float dv[4];
#pragma unroll
    for (int v = 0; v < 4; ++v) {
        int gr = row0 + w * 16 + kg * 4 + v;
        dv[v] = (gr < N_NODES) ? dinv[gr] : 0.f;
    }
#pragma unroll
    for (int f = 0; f < 8; ++f)
#pragma unroll
        for (int v = 0; v < 4; ++v) {
            int gr = row0 + w * 16 + kg * 4 + v;
            if (gr < N_NODES)
                h1b[(size_t)gr * HID_DIM + f * 16 + r] = (unsigned short)f2bf(acc[f][v] * dv[v]);
        }
}

// ---------------- layer 1 fused: pure-sum gather -> scale+bias+ReLU -> GEMM2 -> h2b' ----------------

__global__ __launch_bounds__(256) void k_layer1(const unsigned short* __restrict__ h1b,
                                                const float* __restrict__ dinv,
                                                const float* __restrict__ b1,
                                                const float* __restrict__ W2,
                                                const int* __restrict__ row_ptr,
                                                const int* __restrict__ csr,
                                                unsigned short* __restrict__ h2b) {
    __shared__ float W2s[HID_DIM * OUT_DIM];  // 20 KB
    __shared__ float hs[4][HID_DIM];
    const int tid = threadIdx.x;
    for (int i = tid; i < HID_DIM * OUT_DIM; i += 256) W2s[i] = W2[i];
    __syncthreads();

    const int w    = tid >> 6;
    const int lane = tid & 63;
    const int c0   = lane * 2;

    for (int g = blockIdx.x; g < N_NODES / 4; g += gridDim.x) {
        const int node = g * 4 + w;
        const float di = dinv[node];

        unsigned int us = *(const unsigned int*)(h1b + (size_t)node * HID_DIM + c0);
        float a0 = bf2f((unsigned short)us);
        float a1 = bf2f((unsigned short)(us >> 16));

        const int jb = row_ptr[node];
        const int je = row_ptr[node + 1];
        for (int j = jb; j < je; j += 8) {
            int idx[8];
#pragma unroll
            for (int u = 0; u < 8; ++u) {
                int jj = j + u;
                idx[u] = csr[jj < je ? jj : je - 1];
            }
            unsigned int uu[8];
#pragma unroll
            for (int u = 0; u < 8; ++u)
                uu[u] = *(const unsigned int*)(h1b + (size_t)idx[u] * HID_DIM + c0);
#pragma unroll
            for (int u = 0; u < 8; ++u) {
                bool ok = (j + u) < je;
                a0 += ok ? bf2f((unsigned short)uu[u]) : 0.f;
                a1 += ok ? bf2f((unsigned short)(uu[u] >> 16)) : 0.f;
            }
        }

        hs[w][c0]     = fmaxf(fmaf(di, a0, b1[c0]), 0.f);
        hs[w][c0 + 1] = fmaxf(fmaf(di, a1, b1[c0 + 1]), 0.f);
        // hs[w] is wave-private; per-wave DS ordering suffices

        if (lane < OUT_DIM) {
            float acc = 0.f;
#pragma unroll 8
            for (int k = 0; k < HID_DIM; ++k)
                acc = fmaf(hs[w][k], W2s[k * OUT_DIM + lane], acc);
            h2b[(size_t)node * H2_STRIDE + lane] = (unsigned short)f2bf(acc * di);
        }
    }
}

// ---------------- gather layer 2 (pure sum) + bias + log_softmax -> out ----------------

__global__ __launch_bounds__(256) void k_gather2(const unsigned short* __restrict__ h2b,
                                                 const float* __restrict__ dinv,
                                                 const float* __restrict__ b2,
                                                 const int* __restrict__ row_ptr,
                                                 const int* __restrict__ csr,
                                                 float* __restrict__ out) {
    const int node = blockIdx.x * 4 + (threadIdx.x >> 6);
    const int lane = threadIdx.x & 63;
    const bool act = lane < OUT_DIM;
    const float di = dinv[node];

    float a = bf2f(h2b[(size_t)node * H2_STRIDE + lane]);

    const int jb = row_ptr[node];
    const int je = row_ptr[node + 1];
    for (int j = jb; j < je; j += 8) {
        int idx[8];
#pragma unroll
        for (int u = 0; u < 8; ++u) {
            int jj = j + u;
            idx[u] = csr[jj < je ? jj : je - 1];
        }
        unsigned short hv[8];
#pragma unroll
        for (int u = 0; u < 8; ++u)
            hv[u] = h2b[(size_t)idx[u] * H2_STRIDE + lane];
#pragma unroll
        for (int u = 0; u < 8; ++u)
            a += ((j + u) < je) ? bf2f(hv[u]) : 0.f;
    }

    float v = act ? fmaf(di, a, b2[lane]) : -INFINITY;

    float m = v;
#pragma unroll
    for (int off = 32; off > 0; off >>= 1) m = fmaxf(m, __shfl_xor(m, off));
    float ex = act ? expf(v - m) : 0.f;
    float s = ex;
#pragma unroll
    for (int off = 32; off > 0; off >>= 1) s += __shfl_xor(s, off);
    float ls = logf(s);
    if (act) out[(long long)node * OUT_DIM + lane] = v - m - ls;
}

// ---------------- launch ----------------

extern "C" void kernel_launch(void* const* d_in, const int* in_sizes, int n_in,
                              void* d_out, int out_size, void* d_ws, size_t ws_size,
                              hipStream_t stream) {
    const float* x  = (const float*)d_in[0];
    const int*   ei = (const int*)d_in[1];
    const float* W1 = (const float*)d_in[2];
    const float* b1 = (const float*)d_in[3];
    const float* W2 = (const float*)d_in[4];
    const float* b2 = (const float*)d_in[5];
    float* out = (float*)d_out;

    const int* esrc = ei;
    const int* edst = ei + N_EDGES;

    char* w = (char*)d_ws;
    int*    gcursor     = (int*)w;   w += sizeof(int) * 256;
    int*    bucket_base = (int*)w;   w += sizeof(int) * 256;
    int*    row_ptr     = (int*)w;   w += sizeof(int) * (N_NODES + 4);
    float*  dinv        = (float*)w; w += sizeof(float) * N_NODES;
    int2*   part        = (int2*)w;  w += sizeof(int2) * (size_t)NB * BCAP;   // 25.7 MB
    int*    csr         = (int*)w;   w += sizeof(int) * N_EDGES;              // 6.4 MB
    unsigned short* h1b = (unsigned short*)w;  w += sizeof(short) * (size_t)N_NODES * HID_DIM;
    unsigned short* h2b = (unsigned short*)w;  w += sizeof(short) * (size_t)N_NODES * H2_STRIDE;
    unsigned short* w1t = (unsigned short*)w;  w += sizeof(short) * HID_DIM * IN_DIM;

    // CSR build: partition -> scan -> per-bucket counting sort (also emits row_ptr, dinv)
    k_initcur<<<1, 256, 0, stream>>>(gcursor);
    k_part<<<NPB, 256, 0, stream>>>(esrc, edst, gcursor, part);
    k_bscan<<<1, 256, 0, stream>>>(gcursor, bucket_base, row_ptr);
    k_bucket<<<NB, 256, 0, stream>>>(part, bucket_base, row_ptr, dinv, csr);

    // layer 1 GEMM via MFMA (pre-scaled by dinv)
    k_w1t<<<HID_DIM, IN_DIM, 0, stream>>>(W1, w1t);
    k_gemm1_mfma<<<(N_NODES + 63) / 64, 256, 0, stream>>>(x, w1t, dinv, h1b);

    // fused gather1 + ReLU + GEMM2
    k_layer1<<<2048, 256, 0, stream>>>(h1b, dinv, b1, W2, row_ptr, csr, h2b);

    // gather2 + log_softmax
    k_gather2<<<N_NODES / 4, 256, 0, stream>>>(h2b, dinv, b2, row_ptr, csr, out);
}

// Round 7
// 180.476 us; speedup vs baseline: 6.4661x; 1.1963x over previous
//
#include <hip/hip_runtime.h>
#include <math.h>

#define N_NODES 50000
#define N_EDGES 1600000
#define IN_DIM 256
#define HID_DIM 128
#define OUT_DIM 40
#define H2_STRIDE 64
#define ZROW N_NODES   // dedicated all-zero row index for CSR padding

#define NB 196         // dst buckets of 256 nodes
#define BCAP 10240     // part[] slots per bucket (avg 8163, sigma ~90 -> 23 sigma)
#define SEGSTRIDE 12288  // padded csr segment stride (max padded <= cnt + 8*256)
#define PCHUNK 8192
#define NPB ((N_EDGES + PCHUNK - 1) / PCHUNK)  // 196

typedef __attribute__((ext_vector_type(8))) short bf16x8;
typedef __attribute__((ext_vector_type(4))) float f32x4;

// ---------------- bf16 helpers (RNE) ----------------
__device__ __forceinline__ unsigned int f2bf(float f) {
    unsigned int u = __float_as_uint(f);
    unsigned int r = u + 0x7FFFu + ((u >> 16) & 1u);
    return r >> 16;
}
__device__ __forceinline__ float bf2f(unsigned short s) {
    return __uint_as_float(((unsigned int)s) << 16);
}

// ---------------- init: gcursor bases + zero rows ----------------
__global__ void k_init(int* __restrict__ gcursor,
                       unsigned short* __restrict__ h1b,
                       unsigned short* __restrict__ h2b) {
    int i = threadIdx.x;
    if (i < NB) gcursor[i] = i * BCAP;
    if (i < HID_DIM) h1b[(size_t)ZROW * HID_DIM + i] = 0;
    if (i < H2_STRIDE) h2b[(size_t)ZROW * H2_STRIDE + i] = 0;
}

// ---------------- partition edges into 196 dst-buckets ----------------
__global__ __launch_bounds__(256) void k_part(const int* __restrict__ src,
                                              const int* __restrict__ dst,
                                              int* __restrict__ gcursor,
                                              int2* __restrict__ part) {
    __shared__ int hist[NB];
    __shared__ int lcur[NB];
    const int tid = threadIdx.x;
    const int base = blockIdx.x * PCHUNK;
    const int n = min(PCHUNK, N_EDGES - base);

    for (int i = tid; i < NB; i += 256) hist[i] = 0;
    __syncthreads();
    for (int i = tid; i < n; i += 256)
        atomicAdd(&hist[dst[base + i] >> 8], 1);
    __syncthreads();
    for (int i = tid; i < NB; i += 256)
        lcur[i] = atomicAdd(&gcursor[i], hist[i]);
    __syncthreads();
    for (int i = tid; i < n; i += 256) {
        int d = dst[base + i];
        int g = d >> 8;
        int pos = atomicAdd(&lcur[g], 1);
        part[pos] = make_int2(src[base + i], d);
    }
}

// ---------------- per-bucket counting sort: row_beg/row_end/dinv + padded csr ----------------
__global__ __launch_bounds__(256) void k_bucket(const int2* __restrict__ part,
                                                const int* __restrict__ gcursor,
                                                int* __restrict__ row_beg,
                                                int* __restrict__ row_end,
                                                float* __restrict__ dinv,
                                                int* __restrict__ csr) {
    __shared__ int hist[256];
    __shared__ int sh[256];
    __shared__ int cur[256];
    const int g = blockIdx.x;
    const int tid = threadIdx.x;
    const int ebase = g * BCAP;
    const int ecnt = gcursor[g] - ebase;
    const int cbase = g * SEGSTRIDE;

    hist[tid] = 0;
    __syncthreads();
    for (int i = tid; i < ecnt; i += 256)
        atomicAdd(&hist[part[ebase + i].y & 255], 1);
    __syncthreads();

    int own = hist[tid];
    int pcnt = (own + 7) & ~7;  // pad each node's segment to x8
    sh[tid] = pcnt;
    __syncthreads();
    for (int off = 1; off < 256; off <<= 1) {
        int t = (tid >= off) ? sh[tid - off] : 0;
        __syncthreads();
        sh[tid] += t;
        __syncthreads();
    }
    int pexcl = sh[tid] - pcnt;

    int node = (g << 8) + tid;
    if (node < N_NODES) {
        row_beg[node] = cbase + pexcl;
        row_end[node] = cbase + pexcl + pcnt;
        dinv[node] = rsqrtf((float)own + 1.0f);  // +1 self-loop
    }
    cur[tid] = cbase + pexcl;
    // fill pad slots with zero-row index (disjoint from scatter targets)
    for (int p = own; p < pcnt; ++p) csr[cbase + pexcl + p] = ZROW;
    __syncthreads();

    for (int i = tid; i < ecnt; i += 256) {
        int2 p = part[ebase + i];
        int pos = atomicAdd(&cur[p.y & 255], 1);
        csr[pos] = p.x;
    }
}

// ---------------- W1^T bf16 [128][256] ----------------
__global__ __launch_bounds__(256) void k_w1t(const float* __restrict__ W1,
                                             unsigned short* __restrict__ w1t) {
    int c = blockIdx.x;
    int k = threadIdx.x;
    w1t[c * IN_DIM + k] = (unsigned short)f2bf(W1[k * HID_DIM + c]);
}

// ---------------- GEMM1 (MFMA): h1b[N][128](bf16) = dinv * (x @ W1) ----------------
__global__ __launch_bounds__(256) void k_gemm1_mfma(const float* __restrict__ x,
                                                    const unsigned short* __restrict__ w1t,
                                                    const float* __restrict__ dinv,
                                                    unsigned short* __restrict__ h1b) {
    __shared__ unsigned short Asub[64 * 32];
    __shared__ unsigned short Bsub[128 * 32];
    const int tid  = threadIdx.x;
    const int w    = tid >> 6;
    const int lane = tid & 63;
    const int row0 = blockIdx.x * 64;
    const int r  = lane & 15;
    const int kg = lane >> 4;

    f32x4 acc[8] = {};

    for (int k0 = 0; k0 < IN_DIM; k0 += 32) {
        {
            int ar = tid >> 2, as = tid & 3;
            int asw = as ^ (ar & 3);
            uint4 pk = make_uint4(0, 0, 0, 0);
            int grow = row0 + ar;
            if (grow < N_NODES) {
                const float4* p = (const float4*)(x + (size_t)grow * IN_DIM + k0 + as * 8);
                float4 v0 = p[0], v1 = p[1];
                pk.x = f2bf(v0.x) | (f2bf(v0.y) << 16);
                pk.y = f2bf(v0.z) | (f2bf(v0.w) << 16);
                pk.z = f2bf(v1.x) | (f2bf(v1.y) << 16);
                pk.w = f2bf(v1.z) | (f2bf(v1.w) << 16);
            }
            *(uint4*)(Asub + ar * 32 + asw * 8) = pk;
        }
#pragma unroll
        for (int i = 0; i < 2; ++i) {
            int q = tid + i * 256;
            int col = q >> 2, slot = q & 3;
            int sl2 = slot ^ (col & 3);
            *(uint4*)(Bsub + col * 32 + sl2 * 8) =
                *(const uint4*)(w1t + (size_t)col * IN_DIM + k0 + slot * 8);
        }
        __syncthreads();

        bf16x8 af = *(const bf16x8*)(Asub + (w * 16 + r) * 32 + ((kg ^ (r & 3)) * 8));
#pragma unroll
        for (int f = 0; f < 8; ++f) {
            bf16x8 bfr = *(const bf16x8*)(Bsub + (f * 16 + r) * 32 + ((kg ^ (r & 3)) * 8));
            acc[f] = __builtin_amdgcn_mfma_f32_16x16x32_bf16(af, bfr, acc[f], 0, 0, 0);
        }
        __syncthreads();
    }

    float dv[4];
#pragma unroll
    for (int v = 0; v < 4; ++v) {
        int gr = row0 + w * 16 + kg * 4 + v;
        dv[v] = (gr < N_NODES) ? dinv[gr] : 0.f;
    }
#pragma unroll
    for (int f = 0; f < 8; ++f)
#pragma unroll
        for (int v = 0; v < 4; ++v) {
            int gr = row0 + w * 16 + kg * 4 + v;
            if (gr < N_NODES)
                h1b[(size_t)gr * HID_DIM + f * 16 + r] = (unsigned short)f2bf(acc[f][v] * dv[v]);
        }
}

// ---------------- layer 1 fused: unmasked pure-sum gather -> scale+bias+ReLU -> GEMM2 ----------------
__global__ __launch_bounds__(256) void k_layer1(const unsigned short* __restrict__ h1b,
                                                const float* __restrict__ dinv,
                                                const float* __restrict__ b1,
                                                const float* __restrict__ W2,
                                                const int* __restrict__ row_beg,
                                                const int* __restrict__ row_end,
                                                const int* __restrict__ csr,
                                                unsigned short* __restrict__ h2b) {
    __shared__ unsigned short W2s[HID_DIM * OUT_DIM];  // 10 KB (bf16)
    __shared__ float hs[4][HID_DIM];                   // 2 KB
    const int tid = threadIdx.x;
    for (int i = tid; i < HID_DIM * OUT_DIM; i += 256)
        W2s[i] = (unsigned short)f2bf(W2[i]);
    __syncthreads();

    const int w    = tid >> 6;
    const int lane = tid & 63;
    const int c0   = lane * 2;

    for (int g = blockIdx.x; g < N_NODES / 4; g += gridDim.x) {
        const int node = g * 4 + w;
        const float di = dinv[node];

        unsigned int us = *(const unsigned int*)(h1b + (size_t)node * HID_DIM + c0);
        float a0 = bf2f((unsigned short)us);
        float a1 = bf2f((unsigned short)(us >> 16));

        const int jb = row_beg[node];
        const int je = row_end[node];
        for (int j = jb; j < je; j += 8) {
            int4 i0 = *(const int4*)(csr + j);
            int4 i1 = *(const int4*)(csr + j + 4);
            unsigned int uu[8];
            uu[0] = *(const unsigned int*)(h1b + (size_t)i0.x * HID_DIM + c0);
            uu[1] = *(const unsigned int*)(h1b + (size_t)i0.y * HID_DIM + c0);
            uu[2] = *(const unsigned int*)(h1b + (size_t)i0.z * HID_DIM + c0);
            uu[3] = *(const unsigned int*)(h1b + (size_t)i0.w * HID_DIM + c0);
            uu[4] = *(const unsigned int*)(h1b + (size_t)i1.x * HID_DIM + c0);
            uu[5] = *(const unsigned int*)(h1b + (size_t)i1.y * HID_DIM + c0);
            uu[6] = *(const unsigned int*)(h1b + (size_t)i1.z * HID_DIM + c0);
            uu[7] = *(const unsigned int*)(h1b + (size_t)i1.w * HID_DIM + c0);
#pragma unroll
            for (int u = 0; u < 8; ++u) {
                a0 += bf2f((unsigned short)uu[u]);
                a1 += bf2f((unsigned short)(uu[u] >> 16));
            }
        }

        hs[w][c0]     = fmaxf(fmaf(di, a0, b1[c0]), 0.f);
        hs[w][c0 + 1] = fmaxf(fmaf(di, a1, b1[c0 + 1]), 0.f);
        // hs[w] is wave-private; per-wave DS ordering suffices

        if (lane < OUT_DIM) {
            float acc = 0.f;
#pragma unroll 8
            for (int k = 0; k < HID_DIM; ++k)
                acc = fmaf(hs[w][k], bf2f(W2s[k * OUT_DIM + lane]), acc);
            h2b[(size_t)node * H2_STRIDE + lane] = (unsigned short)f2bf(acc * di);
        }
    }
}

// ---------------- gather layer 2 (unmasked pure sum) + bias + log_softmax ----------------
__global__ __launch_bounds__(256) void k_gather2(const unsigned short* __restrict__ h2b,
                                                 const float* __restrict__ dinv,
                                                 const float* __restrict__ b2,
                                                 const int* __restrict__ row_beg,
                                                 const int* __restrict__ row_end,
                                                 const int* __restrict__ csr,
                                                 float* __restrict__ out) {
    const int node = blockIdx.x * 4 + (threadIdx.x >> 6);
    const int lane = threadIdx.x & 63;
    const bool act = lane < OUT_DIM;
    const float di = dinv[node];

    float a = bf2f(h2b[(size_t)node * H2_STRIDE + lane]);  // pad lanes read garbage; masked below

    const int jb = row_beg[node];
    const int je = row_end[node];
    for (int j = jb; j < je; j += 8) {
        int4 i0 = *(const int4*)(csr + j);
        int4 i1 = *(const int4*)(csr + j + 4);
        unsigned short hv[8];
        hv[0] = h2b[(size_t)i0.x * H2_STRIDE + lane];
        hv[1] = h2b[(size_t)i0.y * H2_STRIDE + lane];
        hv[2] = h2b[(size_t)i0.z * H2_STRIDE + lane];
        hv[3] = h2b[(size_t)i0.w * H2_STRIDE + lane];
        hv[4] = h2b[(size_t)i1.x * H2_STRIDE + lane];
        hv[5] = h2b[(size_t)i1.y * H2_STRIDE + lane];
        hv[6] = h2b[(size_t)i1.z * H2_STRIDE + lane];
        hv[7] = h2b[(size_t)i1.w * H2_STRIDE + lane];
#pragma unroll
        for (int u = 0; u < 8; ++u) a += bf2f(hv[u]);
    }

    float v = act ? fmaf(di, a, b2[lane]) : -INFINITY;
    float m = v;
#pragma unroll
    for (int off = 32; off > 0; off >>= 1) m = fmaxf(m, __shfl_xor(m, off));
    float ex = act ? expf(v - m) : 0.f;
    float s = ex;
#pragma unroll
    for (int off = 32; off > 0; off >>= 1) s += __shfl_xor(s, off);
    float ls = logf(s);
    if (act) out[(long long)node * OUT_DIM + lane] = v - m - ls;
}

// ---------------- launch ----------------
extern "C" void kernel_launch(void* const* d_in, const int* in_sizes, int n_in,
                              void* d_out, int out_size, void* d_ws, size_t ws_size,
                              hipStream_t stream) {
    const float* x  = (const float*)d_in[0];
    const int*   ei = (const int*)d_in[1];
    const float* W1 = (const float*)d_in[2];
    const float* b1 = (const float*)d_in[3];
    const float* W2 = (const float*)d_in[4];
    const float* b2 = (const float*)d_in[5];
    float* out = (float*)d_out;

    const int* esrc = ei;
    const int* edst = ei + N_EDGES;

    char* w = (char*)d_ws;
    int2*   part    = (int2*)w;   w += sizeof(int2) * (size_t)NB * BCAP;      // 16.1 MB
    int*    csr     = (int*)w;    w += sizeof(int) * (size_t)NB * SEGSTRIDE;  // 9.6 MB
    int*    row_beg = (int*)w;    w += sizeof(int) * 50048;
    int*    row_end = (int*)w;    w += sizeof(int) * 50048;
    float*  dinv    = (float*)w;  w += sizeof(float) * 50048;
    int*    gcursor = (int*)w;    w += sizeof(int) * 256;
    unsigned short* h1b = (unsigned short*)w;  w += sizeof(short) * (size_t)50048 * HID_DIM;
    unsigned short* h2b = (unsigned short*)w;  w += sizeof(short) * (size_t)50048 * H2_STRIDE;
    unsigned short* w1t = (unsigned short*)w;  w += sizeof(short) * HID_DIM * IN_DIM;

    // CSR build (padded segments, fixed stride)
    k_init<<<1, 256, 0, stream>>>(gcursor, h1b, h2b);
    k_part<<<NPB, 256, 0, stream>>>(esrc, edst, gcursor, part);
    k_bucket<<<NB, 256, 0, stream>>>(part, gcursor, row_beg, row_end, dinv, csr);

    // layer 1 GEMM via MFMA (pre-scaled by dinv)
    k_w1t<<<HID_DIM, IN_DIM, 0, stream>>>(W1, w1t);
    k_gemm1_mfma<<<(N_NODES + 63) / 64, 256, 0, stream>>>(x, w1t, dinv, h1b);

    // fused gather1 + ReLU + GEMM2
    k_layer1<<<2048, 256, 0, stream>>>(h1b, dinv, b1, W2, row_beg, row_end, csr, h2b);

    // gather2 + log_softmax
    k_gather2<<<N_NODES / 4, 256, 0, stream>>>(h2b, dinv, b2, row_beg, row_end, csr, out);
}

// Round 8
// 171.141 us; speedup vs baseline: 6.8188x; 1.0545x over previous
//
#include <hip/hip_runtime.h>
#include <math.h>

#define N_NODES 50000
#define N_EDGES 1600000
#define IN_DIM 256
#define HID_DIM 128
#define OUT_DIM 40
#define N2 48          // OUT_DIM padded to MFMA multiple
#define H2_STRIDE 64
#define ZROW N_NODES   // dedicated all-zero row index for CSR padding
#define NROWS 50048    // row allocation (covers pad + tile overrun)

#define NB 196         // dst buckets of 256 nodes
#define BCAP 10240     // part[] slots per bucket
#define SEGSTRIDE 12288
#define PCHUNK 8192
#define NPB ((N_EDGES + PCHUNK - 1) / PCHUNK)  // 196

typedef __attribute__((ext_vector_type(8))) short bf16x8;
typedef __attribute__((ext_vector_type(4))) float f32x4;
typedef __attribute__((ext_vector_type(2))) float f32x2;

// ---------------- bf16 helpers (RNE) ----------------
__device__ __forceinline__ unsigned int f2bf(float f) {
    unsigned int u = __float_as_uint(f);
    unsigned int r = u + 0x7FFFu + ((u >> 16) & 1u);
    return r >> 16;
}
__device__ __forceinline__ float bf2f(unsigned short s) {
    return __uint_as_float(((unsigned int)s) << 16);
}

// ---------------- init: gcursor bases + zero rows ----------------
__global__ void k_init(int* __restrict__ gcursor,
                       unsigned short* __restrict__ h1b,
                       unsigned short* __restrict__ h2b) {
    int i = threadIdx.x;
    if (i < NB) gcursor[i] = i * BCAP;
    if (i < HID_DIM) h1b[(size_t)ZROW * HID_DIM + i] = 0;
    if (i < H2_STRIDE) h2b[(size_t)ZROW * H2_STRIDE + i] = 0;
}

// ---------------- partition edges into 196 dst-buckets ----------------
__global__ __launch_bounds__(256) void k_part(const int* __restrict__ src,
                                              const int* __restrict__ dst,
                                              int* __restrict__ gcursor,
                                              int2* __restrict__ part) {
    __shared__ int hist[NB];
    __shared__ int lcur[NB];
    const int tid = threadIdx.x;
    const int base = blockIdx.x * PCHUNK;
    const int n = min(PCHUNK, N_EDGES - base);

    for (int i = tid; i < NB; i += 256) hist[i] = 0;
    __syncthreads();
    for (int i = tid; i < n; i += 256)
        atomicAdd(&hist[dst[base + i] >> 8], 1);
    __syncthreads();
    for (int i = tid; i < NB; i += 256)
        lcur[i] = atomicAdd(&gcursor[i], hist[i]);
    __syncthreads();
    for (int i = tid; i < n; i += 256) {
        int d = dst[base + i];
        int g = d >> 8;
        int pos = atomicAdd(&lcur[g], 1);
        part[pos] = make_int2(src[base + i], d);
    }
}

// ---------------- per-bucket counting sort: row_beg/row_end/dinv + padded csr ----------------
__global__ __launch_bounds__(256) void k_bucket(const int2* __restrict__ part,
                                                const int* __restrict__ gcursor,
                                                int* __restrict__ row_beg,
                                                int* __restrict__ row_end,
                                                float* __restrict__ dinv,
                                                int* __restrict__ csr) {
    __shared__ int hist[256];
    __shared__ int sh[256];
    __shared__ int cur[256];
    const int g = blockIdx.x;
    const int tid = threadIdx.x;
    const int ebase = g * BCAP;
    const int ecnt = gcursor[g] - ebase;
    const int cbase = g * SEGSTRIDE;

    hist[tid] = 0;
    __syncthreads();
    for (int i = tid; i < ecnt; i += 256)
        atomicAdd(&hist[part[ebase + i].y & 255], 1);
    __syncthreads();

    int own = hist[tid];
    int pcnt = (own + 7) & ~7;  // pad each node's segment to x8
    sh[tid] = pcnt;
    __syncthreads();
    for (int off = 1; off < 256; off <<= 1) {
        int t = (tid >= off) ? sh[tid - off] : 0;
        __syncthreads();
        sh[tid] += t;
        __syncthreads();
    }
    int pexcl = sh[tid] - pcnt;

    int node = (g << 8) + tid;
    if (node < N_NODES) {
        row_beg[node] = cbase + pexcl;
        row_end[node] = cbase + pexcl + pcnt;
        dinv[node] = rsqrtf((float)own + 1.0f);
    }
    cur[tid] = cbase + pexcl;
    for (int p = own; p < pcnt; ++p) csr[cbase + pexcl + p] = ZROW;
    __syncthreads();

    for (int i = tid; i < ecnt; i += 256) {
        int2 p = part[ebase + i];
        int pos = atomicAdd(&cur[p.y & 255], 1);
        csr[pos] = p.x;
    }
}

// ---------------- W1^T bf16 [128][256] ----------------
__global__ __launch_bounds__(256) void k_w1t(const float* __restrict__ W1,
                                             unsigned short* __restrict__ w1t) {
    int c = blockIdx.x;
    int k = threadIdx.x;
    w1t[c * IN_DIM + k] = (unsigned short)f2bf(W1[k * HID_DIM + c]);
}

// ---------------- W2^T bf16 [48][128] (cols 40..47 zero) ----------------
__global__ __launch_bounds__(128) void k_w2t(const float* __restrict__ W2,
                                             unsigned short* __restrict__ w2t) {
    int c = blockIdx.x;   // 0..47
    int k = threadIdx.x;  // 0..127
    w2t[c * HID_DIM + k] = (c < OUT_DIM) ? (unsigned short)f2bf(W2[k * OUT_DIM + c]) : 0;
}

// ---------------- GEMM1 (MFMA): h1b[N][128](bf16) = dinv * (x @ W1) ----------------
__global__ __launch_bounds__(256) void k_gemm1_mfma(const float* __restrict__ x,
                                                    const unsigned short* __restrict__ w1t,
                                                    const float* __restrict__ dinv,
                                                    unsigned short* __restrict__ h1b) {
    __shared__ unsigned short Asub[64 * 32];
    __shared__ unsigned short Bsub[128 * 32];
    const int tid  = threadIdx.x;
    const int w    = tid >> 6;
    const int lane = tid & 63;
    const int row0 = blockIdx.x * 64;
    const int r  = lane & 15;
    const int kg = lane >> 4;

    f32x4 acc[8] = {};

    for (int k0 = 0; k0 < IN_DIM; k0 += 32) {
        {
            int ar = tid >> 2, as = tid & 3;
            int asw = as ^ (ar & 3);
            uint4 pk = make_uint4(0, 0, 0, 0);
            int grow = row0 + ar;
            if (grow < N_NODES) {
                const float4* p = (const float4*)(x + (size_t)grow * IN_DIM + k0 + as * 8);
                float4 v0 = p[0], v1 = p[1];
                pk.x = f2bf(v0.x) | (f2bf(v0.y) << 16);
                pk.y = f2bf(v0.z) | (f2bf(v0.w) << 16);
                pk.z = f2bf(v1.x) | (f2bf(v1.y) << 16);
                pk.w = f2bf(v1.z) | (f2bf(v1.w) << 16);
            }
            *(uint4*)(Asub + ar * 32 + asw * 8) = pk;
        }
#pragma unroll
        for (int i = 0; i < 2; ++i) {
            int q = tid + i * 256;
            int col = q >> 2, slot = q & 3;
            int sl2 = slot ^ (col & 3);
            *(uint4*)(Bsub + col * 32 + sl2 * 8) =
                *(const uint4*)(w1t + (size_t)col * IN_DIM + k0 + slot * 8);
        }
        __syncthreads();

        bf16x8 af = *(const bf16x8*)(Asub + (w * 16 + r) * 32 + ((kg ^ (r & 3)) * 8));
#pragma unroll
        for (int f = 0; f < 8; ++f) {
            bf16x8 bfr = *(const bf16x8*)(Bsub + (f * 16 + r) * 32 + ((kg ^ (r & 3)) * 8));
            acc[f] = __builtin_amdgcn_mfma_f32_16x16x32_bf16(af, bfr, acc[f], 0, 0, 0);
        }
        __syncthreads();
    }

    float dv[4];
#pragma unroll
    for (int v = 0; v < 4; ++v) {
        int gr = row0 + w * 16 + kg * 4 + v;
        dv[v] = (gr < N_NODES) ? dinv[gr] : 0.f;
    }
#pragma unroll
    for (int f = 0; f < 8; ++f)
#pragma unroll
        for (int v = 0; v < 4; ++v) {
            int gr = row0 + w * 16 + kg * 4 + v;
            if (gr < N_NODES)
                h1b[(size_t)gr * HID_DIM + f * 16 + r] = (unsigned short)f2bf(acc[f][v] * dv[v]);
        }
}

// ---------------- layer-1 gather (pure): h1a = relu(di*sum + b1), bf16 ----------------
__global__ __launch_bounds__(256) void k_layer1(const unsigned short* __restrict__ h1b,
                                                const float* __restrict__ dinv,
                                                const float* __restrict__ b1,
                                                const int* __restrict__ row_beg,
                                                const int* __restrict__ row_end,
                                                const int* __restrict__ csr,
                                                unsigned short* __restrict__ h1a) {
    const int w    = threadIdx.x >> 6;
    const int lane = threadIdx.x & 63;
    const int c0   = lane * 2;
    const float bb0 = b1[c0], bb1 = b1[c0 + 1];

    const int node = blockIdx.x * 4 + w;
    const float di = dinv[node];

    unsigned int us = *(const unsigned int*)(h1b + (size_t)node * HID_DIM + c0);
    f32x2 acc;
    acc.x = bf2f((unsigned short)us);
    acc.y = bf2f((unsigned short)(us >> 16));

    int j = row_beg[node];
    const int je = row_end[node];
    for (; j + 16 <= je; j += 16) {
        int4 i0 = *(const int4*)(csr + j);
        int4 i1 = *(const int4*)(csr + j + 4);
        int4 i2 = *(const int4*)(csr + j + 8);
        int4 i3 = *(const int4*)(csr + j + 12);
        unsigned int uu[16];
        uu[0]  = *(const unsigned int*)(h1b + (size_t)i0.x * HID_DIM + c0);
        uu[1]  = *(const unsigned int*)(h1b + (size_t)i0.y * HID_DIM + c0);
        uu[2]  = *(const unsigned int*)(h1b + (size_t)i0.z * HID_DIM + c0);
        uu[3]  = *(const unsigned int*)(h1b + (size_t)i0.w * HID_DIM + c0);
        uu[4]  = *(const unsigned int*)(h1b + (size_t)i1.x * HID_DIM + c0);
        uu[5]  = *(const unsigned int*)(h1b + (size_t)i1.y * HID_DIM + c0);
        uu[6]  = *(const unsigned int*)(h1b + (size_t)i1.z * HID_DIM + c0);
        uu[7]  = *(const unsigned int*)(h1b + (size_t)i1.w * HID_DIM + c0);
        uu[8]  = *(const unsigned int*)(h1b + (size_t)i2.x * HID_DIM + c0);
        uu[9]  = *(const unsigned int*)(h1b + (size_t)i2.y * HID_DIM + c0);
        uu[10] = *(const unsigned int*)(h1b + (size_t)i2.z * HID_DIM + c0);
        uu[11] = *(const unsigned int*)(h1b + (size_t)i2.w * HID_DIM + c0);
        uu[12] = *(const unsigned int*)(h1b + (size_t)i3.x * HID_DIM + c0);
        uu[13] = *(const unsigned int*)(h1b + (size_t)i3.y * HID_DIM + c0);
        uu[14] = *(const unsigned int*)(h1b + (size_t)i3.z * HID_DIM + c0);
        uu[15] = *(const unsigned int*)(h1b + (size_t)i3.w * HID_DIM + c0);
#pragma unroll
        for (int u = 0; u < 16; ++u) {
            f32x2 t;
            t.x = __uint_as_float(uu[u] << 16);
            t.y = __uint_as_float(uu[u] & 0xffff0000u);
            acc += t;
        }
    }
    if (j < je) {  // exactly one 8-batch remains
        int4 i0 = *(const int4*)(csr + j);
        int4 i1 = *(const int4*)(csr + j + 4);
        unsigned int uu[8];
        uu[0] = *(const unsigned int*)(h1b + (size_t)i0.x * HID_DIM + c0);
        uu[1] = *(const unsigned int*)(h1b + (size_t)i0.y * HID_DIM + c0);
        uu[2] = *(const unsigned int*)(h1b + (size_t)i0.z * HID_DIM + c0);
        uu[3] = *(const unsigned int*)(h1b + (size_t)i0.w * HID_DIM + c0);
        uu[4] = *(const unsigned int*)(h1b + (size_t)i1.x * HID_DIM + c0);
        uu[5] = *(const unsigned int*)(h1b + (size_t)i1.y * HID_DIM + c0);
        uu[6] = *(const unsigned int*)(h1b + (size_t)i1.z * HID_DIM + c0);
        uu[7] = *(const unsigned int*)(h1b + (size_t)i1.w * HID_DIM + c0);
#pragma unroll
        for (int u = 0; u < 8; ++u) {
            f32x2 t;
            t.x = __uint_as_float(uu[u] << 16);
            t.y = __uint_as_float(uu[u] & 0xffff0000u);
            acc += t;
        }
    }

    float r0 = fmaxf(fmaf(di, acc.x, bb0), 0.f);
    float r1 = fmaxf(fmaf(di, acc.y, bb1), 0.f);
    *(unsigned int*)(h1a + (size_t)node * HID_DIM + c0) = f2bf(r0) | (f2bf(r1) << 16);
}

// ---------------- GEMM2 (MFMA): h2b[N][64pad](bf16) = dinv * (h1a @ W2) ----------------
// 64 rows per block (4 waves x 16 rows); B (w2t 48x128) staged swizzled in LDS.
__global__ __launch_bounds__(256) void k_gemm2_mfma(const unsigned short* __restrict__ h1a,
                                                    const unsigned short* __restrict__ w2t,
                                                    const float* __restrict__ dinv,
                                                    unsigned short* __restrict__ h2b) {
    __shared__ unsigned short Bs[N2 * HID_DIM];  // 12 KB
    const int tid = threadIdx.x;
    // stage w2t with 16B-slot swizzle: slot' = slot ^ (row&7); 16 slots/row
#pragma unroll
    for (int i = tid; i < N2 * HID_DIM / 8; i += 256) {
        int row = i >> 4, slot = i & 15;
        *(uint4*)(Bs + row * HID_DIM + (slot ^ (row & 7)) * 8) =
            *(const uint4*)(w2t + (size_t)row * HID_DIM + slot * 8);
    }
    __syncthreads();

    const int w    = tid >> 6;
    const int lane = tid & 63;
    const int r  = lane & 15;
    const int kg = lane >> 4;
    const int row0 = blockIdx.x * 64 + w * 16;

    // B frags: lane holds B[k=ks*32+kg*8 .. +7][col=f*16+r] from w2t[col][k]
    bf16x8 bfr[4][3];
#pragma unroll
    for (int ks = 0; ks < 4; ++ks)
#pragma unroll
        for (int f = 0; f < 3; ++f) {
            int row = f * 16 + r;
            int slot = ks * 4 + kg;
            bfr[ks][f] = *(const bf16x8*)(Bs + row * HID_DIM + (slot ^ (row & 7)) * 8);
        }

    f32x4 acc[3] = {};
#pragma unroll
    for (int ks = 0; ks < 4; ++ks) {
        bf16x8 af = *(const bf16x8*)(h1a + (size_t)(row0 + r) * HID_DIM + ks * 32 + kg * 8);
#pragma unroll
        for (int f = 0; f < 3; ++f)
            acc[f] = __builtin_amdgcn_mfma_f32_16x16x32_bf16(af, bfr[ks][f], acc[f], 0, 0, 0);
    }

    // D: row_in_tile = kg*4+v, col = f*16+r
    float dv[4];
#pragma unroll
    for (int v = 0; v < 4; ++v) {
        int gr = row0 + kg * 4 + v;
        dv[v] = (gr < N_NODES) ? dinv[gr] : 0.f;
    }
#pragma unroll
    for (int f = 0; f < 3; ++f) {
        int col = f * 16 + r;
        if (col < OUT_DIM) {
#pragma unroll
            for (int v = 0; v < 4; ++v) {
                int gr = row0 + kg * 4 + v;
                if (gr < N_NODES)
                    h2b[(size_t)gr * H2_STRIDE + col] = (unsigned short)f2bf(acc[f][v] * dv[v]);
            }
        }
    }
}

// ---------------- gather layer 2 (unmasked pure sum) + bias + log_softmax ----------------
__global__ __launch_bounds__(256) void k_gather2(const unsigned short* __restrict__ h2b,
                                                 const float* __restrict__ dinv,
                                                 const float* __restrict__ b2,
                                                 const int* __restrict__ row_beg,
                                                 const int* __restrict__ row_end,
                                                 const int* __restrict__ csr,
                                                 float* __restrict__ out) {
    const int node = blockIdx.x * 4 + (threadIdx.x >> 6);
    const int lane = threadIdx.x & 63;
    const bool act = lane < OUT_DIM;
    const float di = dinv[node];

    float a = bf2f(h2b[(size_t)node * H2_STRIDE + lane]);

    int j = row_beg[node];
    const int je = row_end[node];
    for (; j + 16 <= je; j += 16) {
        int4 i0 = *(const int4*)(csr + j);
        int4 i1 = *(const int4*)(csr + j + 4);
        int4 i2 = *(const int4*)(csr + j + 8);
        int4 i3 = *(const int4*)(csr + j + 12);
        unsigned short hv[16];
        hv[0]  = h2b[(size_t)i0.x * H2_STRIDE + lane];
        hv[1]  = h2b[(size_t)i0.y * H2_STRIDE + lane];
        hv[2]  = h2b[(size_t)i0.z * H2_STRIDE + lane];
        hv[3]  = h2b[(size_t)i0.w * H2_STRIDE + lane];
        hv[4]  = h2b[(size_t)i1.x * H2_STRIDE + lane];
        hv[5]  = h2b[(size_t)i1.y * H2_STRIDE + lane];
        hv[6]  = h2b[(size_t)i1.z * H2_STRIDE + lane];
        hv[7]  = h2b[(size_t)i1.w * H2_STRIDE + lane];
        hv[8]  = h2b[(size_t)i2.x * H2_STRIDE + lane];
        hv[9]  = h2b[(size_t)i2.y * H2_STRIDE + lane];
        hv[10] = h2b[(size_t)i2.z * H2_STRIDE + lane];
        hv[11] = h2b[(size_t)i2.w * H2_STRIDE + lane];
        hv[12] = h2b[(size_t)i3.x * H2_STRIDE + lane];
        hv[13] = h2b[(size_t)i3.y * H2_STRIDE + lane];
        hv[14] = h2b[(size_t)i3.z * H2_STRIDE + lane];
        hv[15] = h2b[(size_t)i3.w * H2_STRIDE + lane];
#pragma unroll
        for (int u = 0; u < 16; ++u) a += bf2f(hv[u]);
    }
    if (j < je) {
        int4 i0 = *(const int4*)(csr + j);
        int4 i1 = *(const int4*)(csr + j + 4);
        unsigned short hv[8];
        hv[0] = h2b[(size_t)i0.x * H2_STRIDE + lane];
        hv[1] = h2b[(size_t)i0.y * H2_STRIDE + lane];
        hv[2] = h2b[(size_t)i0.z * H2_STRIDE + lane];
        hv[3] = h2b[(size_t)i0.w * H2_STRIDE + lane];
        hv[4] = h2b[(size_t)i1.x * H2_STRIDE + lane];
        hv[5] = h2b[(size_t)i1.y * H2_STRIDE + lane];
        hv[6] = h2b[(size_t)i1.z * H2_STRIDE + lane];
        hv[7] = h2b[(size_t)i1.w * H2_STRIDE + lane];
#pragma unroll
        for (int u = 0; u < 8; ++u) a += bf2f(hv[u]);
    }

    float v = act ? fmaf(di, a, b2[lane]) : -INFINITY;
    float m = v;
#pragma unroll
    for (int off = 32; off > 0; off >>= 1) m = fmaxf(m, __shfl_xor(m, off));
    float ex = act ? expf(v - m) : 0.f;
    float s = ex;
#pragma unroll
    for (int off = 32; off > 0; off >>= 1) s += __shfl_xor(s, off);
    float ls = logf(s);
    if (act) out[(long long)node * OUT_DIM + lane] = v - m - ls;
}

// ---------------- launch ----------------
extern "C" void kernel_launch(void* const* d_in, const int* in_sizes, int n_in,
                              void* d_out, int out_size, void* d_ws, size_t ws_size,
                              hipStream_t stream) {
    const float* x  = (const float*)d_in[0];
    const int*   ei = (const int*)d_in[1];
    const float* W1 = (const float*)d_in[2];
    const float* b1 = (const float*)d_in[3];
    const float* W2 = (const float*)d_in[4];
    const float* b2 = (const float*)d_in[5];
    float* out = (float*)d_out;

    const int* esrc = ei;
    const int* edst = ei + N_EDGES;

    char* w = (char*)d_ws;
    int2*   part    = (int2*)w;   w += sizeof(int2) * (size_t)NB * BCAP;      // 16.1 MB
    int*    csr     = (int*)w;    w += sizeof(int) * (size_t)NB * SEGSTRIDE;  // 9.6 MB
    int*    row_beg = (int*)w;    w += sizeof(int) * NROWS;
    int*    row_end = (int*)w;    w += sizeof(int) * NROWS;
    float*  dinv    = (float*)w;  w += sizeof(float) * NROWS;
    int*    gcursor = (int*)w;    w += sizeof(int) * 256;
    unsigned short* h1b = (unsigned short*)w;  w += sizeof(short) * (size_t)NROWS * HID_DIM;
    unsigned short* h1a = (unsigned short*)w;  w += sizeof(short) * (size_t)NROWS * HID_DIM;
    unsigned short* h2b = (unsigned short*)w;  w += sizeof(short) * (size_t)NROWS * H2_STRIDE;
    unsigned short* w1t = (unsigned short*)w;  w += sizeof(short) * HID_DIM * IN_DIM;
    unsigned short* w2t = (unsigned short*)w;  w += sizeof(short) * N2 * HID_DIM;

    // CSR build (padded segments, fixed stride)
    k_init<<<1, 256, 0, stream>>>(gcursor, h1b, h2b);
    k_part<<<NPB, 256, 0, stream>>>(esrc, edst, gcursor, part);
    k_bucket<<<NB, 256, 0, stream>>>(part, gcursor, row_beg, row_end, dinv, csr);

    // weights prep
    k_w1t<<<HID_DIM, IN_DIM, 0, stream>>>(W1, w1t);
    k_w2t<<<N2, HID_DIM, 0, stream>>>(W2, w2t);

    // layer 1 GEMM via MFMA (pre-scaled by dinv)
    k_gemm1_mfma<<<(N_NODES + 63) / 64, 256, 0, stream>>>(x, w1t, dinv, h1b);

    // gather1 (+ReLU) -> h1a
    k_layer1<<<N_NODES / 4, 256, 0, stream>>>(h1b, dinv, b1, row_beg, row_end, csr, h1a);

    // GEMM2 via MFMA -> h2b (pre-scaled by dinv)
    k_gemm2_mfma<<<NROWS / 64, 256, 0, stream>>>(h1a, w2t, dinv, h2b);

    // gather2 + log_softmax
    k_gather2<<<N_NODES / 4, 256, 0, stream>>>(h2b, dinv, b2, row_beg, row_end, csr, out);
}